// Round 1
// baseline (1856.819 us; speedup 1.0000x reference)
//
#include <hip/hip_runtime.h>

#define N_NODES 100000
#define N_EDGES 3200000
#define DIM 128
#define NG 64

// ---------------- degrees ----------------
__global__ void k_degrees(const int* __restrict__ src, const int* __restrict__ dst,
                          int* __restrict__ degi_out, int* __restrict__ degi_in) {
    int e = blockIdx.x * 256 + threadIdx.x;
    if (e < N_EDGES) {
        atomicAdd(&degi_out[src[e]], 1);
        atomicAdd(&degi_in[dst[e]], 1);
    }
}

// ---------------- norms ----------------
__global__ void k_norms(const int* __restrict__ degi_out, const int* __restrict__ degi_in,
                        float* __restrict__ norm_src, float* __restrict__ norm_dst) {
    int i = blockIdx.x * 256 + threadIdx.x;
    if (i < N_NODES) {
        int a = degi_out[i]; if (a < 1) a = 1;
        int b = degi_in[i];  if (b < 1) b = 1;
        norm_src[i] = rsqrtf((float)a);
        norm_dst[i] = rsqrtf((float)b);
    }
}

// ---------------- exclusive scan of deg_in -> rowptr, cursor (single block) ----------------
__global__ void k_scan(const int* __restrict__ degi_in, int* __restrict__ rowptr,
                       int* __restrict__ cursor) {
    __shared__ int sums[1024];
    int tid = threadIdx.x;
    const int CH = (N_NODES + 1023) / 1024;  // 98
    int beg = tid * CH;
    int end = beg + CH; if (end > N_NODES) end = N_NODES;
    int s = 0;
    for (int i = beg; i < end && i < N_NODES; ++i) s += degi_in[i];
    sums[tid] = s;
    __syncthreads();
    for (int off = 1; off < 1024; off <<= 1) {
        int v = sums[tid];
        int o = (tid >= off) ? sums[tid - off] : 0;
        __syncthreads();
        sums[tid] = v + o;
        __syncthreads();
    }
    int run = (tid > 0) ? sums[tid - 1] : 0;
    for (int i = beg; i < end && i < N_NODES; ++i) {
        rowptr[i] = run; cursor[i] = run; run += degi_in[i];
    }
    if (tid == 1023) rowptr[N_NODES] = sums[1023];
}

// ---------------- CSR fill ----------------
__global__ void k_csr(const int* __restrict__ src, const int* __restrict__ dst,
                      int* __restrict__ cursor, int* __restrict__ col) {
    int e = blockIdx.x * 256 + threadIdx.x;
    if (e < N_EDGES) {
        int d = dst[e];
        int pos = atomicAdd(&cursor[d], 1);
        col[pos] = src[e];
    }
}

// ---------------- SpMM: out[n] = (sum_in-edges in[s]*norm_src[s]) * norm_dst[n] ----------------
__global__ __launch_bounds__(256) void k_spmm(const float* __restrict__ in,
                       const int* __restrict__ rowptr, const int* __restrict__ col,
                       const float* __restrict__ norm_src, const float* __restrict__ norm_dst,
                       float* __restrict__ out) {
    int wave = (blockIdx.x * 256 + threadIdx.x) >> 6;
    int lane = threadIdx.x & 63;
    if (wave >= N_NODES) return;
    int n = wave;
    const float2* in2 = (const float2*)in;
    int jb = rowptr[n], je = rowptr[n + 1];
    float ax = 0.f, ay = 0.f;
    int j = jb;
    for (; j + 4 <= je; j += 4) {
        int s0 = col[j], s1 = col[j + 1], s2 = col[j + 2], s3 = col[j + 3];
        float w0 = norm_src[s0], w1 = norm_src[s1], w2 = norm_src[s2], w3 = norm_src[s3];
        float2 v0 = in2[(size_t)s0 * 64 + lane];
        float2 v1 = in2[(size_t)s1 * 64 + lane];
        float2 v2 = in2[(size_t)s2 * 64 + lane];
        float2 v3 = in2[(size_t)s3 * 64 + lane];
        ax += v0.x * w0; ay += v0.y * w0;
        ax += v1.x * w1; ay += v1.y * w1;
        ax += v2.x * w2; ay += v2.y * w2;
        ax += v3.x * w3; ay += v3.y * w3;
    }
    for (; j < je; ++j) {
        int s = col[j]; float w = norm_src[s];
        float2 v = in2[(size_t)s * 64 + lane];
        ax += v.x * w; ay += v.y * w;
    }
    float nd = norm_dst[n];
    float2* o2 = (float2*)out;
    o2[(size_t)n * 64 + lane] = make_float2(ax * nd, ay * nd);
}

// ---------------- GEMM [N,128] @ [128,128] + bias + relu ----------------
__global__ __launch_bounds__(256) void k_gemm(const float* __restrict__ A,
                      const float* __restrict__ W, const float* __restrict__ bias,
                      float* __restrict__ out) {
    __shared__ float Wl[DIM * DIM];  // 64 KB
    int tid = threadIdx.x;
    for (int i = tid * 4; i < DIM * DIM; i += 256 * 4) {
        *(float4*)&Wl[i] = *(const float4*)&W[i];
    }
    __syncthreads();
    int r0 = blockIdx.x * 128 + (tid >> 4) * 8;
    int c0 = (tid & 15) * 8;
    float bb[8];
    #pragma unroll
    for (int j = 0; j < 8; j++) bb[j] = bias[c0 + j];
    float acc[8][8];
    #pragma unroll
    for (int i = 0; i < 8; i++)
        #pragma unroll
        for (int j = 0; j < 8; j++) acc[i][j] = 0.f;

    for (int k = 0; k < DIM; k += 4) {
        float4 a[8];
        #pragma unroll
        for (int i = 0; i < 8; i++) {
            int r = r0 + i; if (r >= N_NODES) r = N_NODES - 1;
            a[i] = *(const float4*)&A[(size_t)r * DIM + k];
        }
        #pragma unroll
        for (int kk = 0; kk < 4; kk++) {
            float w[8];
            #pragma unroll
            for (int j = 0; j < 8; j++) w[j] = Wl[(k + kk) * DIM + c0 + j];
            #pragma unroll
            for (int i = 0; i < 8; i++) {
                float av = (kk == 0) ? a[i].x : (kk == 1) ? a[i].y : (kk == 2) ? a[i].z : a[i].w;
                #pragma unroll
                for (int j = 0; j < 8; j++) acc[i][j] += av * w[j];
            }
        }
    }
    #pragma unroll
    for (int i = 0; i < 8; i++) {
        int r = r0 + i;
        if (r < N_NODES) {
            float4 o0, o1;
            o0.x = fmaxf(acc[i][0] + bb[0], 0.f);
            o0.y = fmaxf(acc[i][1] + bb[1], 0.f);
            o0.z = fmaxf(acc[i][2] + bb[2], 0.f);
            o0.w = fmaxf(acc[i][3] + bb[3], 0.f);
            o1.x = fmaxf(acc[i][4] + bb[4], 0.f);
            o1.y = fmaxf(acc[i][5] + bb[5], 0.f);
            o1.z = fmaxf(acc[i][6] + bb[6], 0.f);
            o1.w = fmaxf(acc[i][7] + bb[7], 0.f);
            *(float4*)&out[(size_t)r * DIM + c0] = o0;
            *(float4*)&out[(size_t)r * DIM + c0 + 4] = o1;
        }
    }
}

// ---------------- per-graph node counts ----------------
__global__ void k_counts(const int* __restrict__ gids, int* __restrict__ cnt) {
    int i = blockIdx.x * 256 + threadIdx.x;
    if (i < N_NODES) atomicAdd(&cnt[gids[i]], 1);
}

// ---------------- per-graph feature sums (graph_ids sorted -> segment accumulate) ----------------
__global__ void k_graphsum(const float* __restrict__ h, const int* __restrict__ gids,
                           float* __restrict__ hg) {
    int wave = (blockIdx.x * 256 + threadIdx.x) >> 6;
    int lane = threadIdx.x & 63;
    int base = wave * 16;
    if (base >= N_NODES) return;
    const float2* h2 = (const float2*)h;
    float ax = 0.f, ay = 0.f;
    int cur = gids[base];
    int end = base + 16; if (end > N_NODES) end = N_NODES;
    for (int nd = base; nd < end; ++nd) {
        int g = gids[nd];
        if (g != cur) {
            atomicAdd(&hg[cur * DIM + 2 * lane], ax);
            atomicAdd(&hg[cur * DIM + 2 * lane + 1], ay);
            ax = 0.f; ay = 0.f; cur = g;
        }
        float2 v = h2[(size_t)nd * 64 + lane];
        ax += v.x; ay += v.y;
    }
    atomicAdd(&hg[cur * DIM + 2 * lane], ax);
    atomicAdd(&hg[cur * DIM + 2 * lane + 1], ay);
}

// ---------------- MLP readout, one wave per graph ----------------
__global__ void k_mlp(const float* __restrict__ hg, const int* __restrict__ cnt,
                      const float* __restrict__ Wm0, const float* __restrict__ bm0,
                      const float* __restrict__ Wm1, const float* __restrict__ bm1,
                      const float* __restrict__ Wm2, const float* __restrict__ bm2,
                      const float* __restrict__ Wm3, const float* __restrict__ bm3,
                      float* __restrict__ out) {
    __shared__ float hb[DIM];
    __shared__ float l0[64];
    __shared__ float l1[32];
    __shared__ float l2[16];
    int g = blockIdx.x;
    int t = threadIdx.x;  // 64 threads = 1 wave
    float c = (float)cnt[g]; if (c < 1.f) c = 1.f;
    float inv = 1.f / c;
    hb[t] = hg[g * DIM + t] * inv;
    hb[t + 64] = hg[g * DIM + t + 64] * inv;
    __syncthreads();
    {
        float acc = bm0[t];
        for (int k = 0; k < 128; k++) acc += hb[k] * Wm0[k * 64 + t];
        l0[t] = fmaxf(acc, 0.f);
    }
    __syncthreads();
    if (t < 32) {
        float acc = bm1[t];
        for (int k = 0; k < 64; k++) acc += l0[k] * Wm1[k * 32 + t];
        l1[t] = fmaxf(acc, 0.f);
    }
    __syncthreads();
    if (t < 16) {
        float acc = bm2[t];
        for (int k = 0; k < 32; k++) acc += l1[k] * Wm2[k * 16 + t];
        l2[t] = fmaxf(acc, 0.f);
    }
    __syncthreads();
    if (t == 0) {
        float acc = bm3[0];
        for (int k = 0; k < 16; k++) acc += l2[k] * Wm3[k];
        out[g] = acc;
    }
}

extern "C" void kernel_launch(void* const* d_in, const int* in_sizes, int n_in,
                              void* d_out, int out_size, void* d_ws, size_t ws_size,
                              hipStream_t stream) {
    const float* feat = (const float*)d_in[0];
    const int*   src  = (const int*)d_in[1];
    const int*   dst  = (const int*)d_in[2];
    const int*   gids = (const int*)d_in[3];
    const float* W1   = (const float*)d_in[5];
    const float* b1   = (const float*)d_in[6];
    const float* W2   = (const float*)d_in[7];
    const float* b2   = (const float*)d_in[8];
    const float* Wm0  = (const float*)d_in[9];
    const float* bm0  = (const float*)d_in[10];
    const float* Wm1  = (const float*)d_in[11];
    const float* bm1  = (const float*)d_in[12];
    const float* Wm2  = (const float*)d_in[13];
    const float* bm2  = (const float*)d_in[14];
    const float* Wm3  = (const float*)d_in[15];
    const float* bm3  = (const float*)d_in[16];
    float* out = (float*)d_out;

    char* ws = (char*)d_ws;
    size_t off = 0;
    auto alloc = [&](size_t bytes) -> void* {
        void* p = ws + off;
        off += (bytes + 511) & ~(size_t)511;
        return p;
    };
    float* norm_src = (float*)alloc((size_t)N_NODES * 4);
    float* norm_dst = (float*)alloc((size_t)N_NODES * 4);
    int* degi_out = (int*)alloc((size_t)N_NODES * 4);
    int* degi_in  = (int*)alloc((size_t)N_NODES * 4);
    int* rowptr   = (int*)alloc((size_t)(N_NODES + 1) * 4);
    int* cursor   = (int*)alloc((size_t)N_NODES * 4);
    int* col      = (int*)alloc((size_t)N_EDGES * 4);
    float* bufA   = (float*)alloc((size_t)N_NODES * DIM * 4);
    float* bufB   = (float*)alloc((size_t)N_NODES * DIM * 4);
    float* hg     = (float*)alloc((size_t)NG * DIM * 4);
    int* cnt      = (int*)alloc((size_t)NG * 4);

    hipMemsetAsync(degi_out, 0, (size_t)N_NODES * 4, stream);
    hipMemsetAsync(degi_in, 0, (size_t)N_NODES * 4, stream);
    hipMemsetAsync(hg, 0, (size_t)NG * DIM * 4, stream);
    hipMemsetAsync(cnt, 0, (size_t)NG * 4, stream);

    int eb = (N_EDGES + 255) / 256;
    int nb = (N_NODES + 255) / 256;
    k_degrees<<<eb, 256, 0, stream>>>(src, dst, degi_out, degi_in);
    k_norms<<<nb, 256, 0, stream>>>(degi_out, degi_in, norm_src, norm_dst);
    k_scan<<<1, 1024, 0, stream>>>(degi_in, rowptr, cursor);
    k_csr<<<eb, 256, 0, stream>>>(src, dst, cursor, col);

    int sb = (N_NODES + 3) / 4;  // 4 waves per 256-thread block, 1 wave per node
    k_spmm<<<sb, 256, 0, stream>>>(feat, rowptr, col, norm_src, norm_dst, bufA);
    k_gemm<<<(N_NODES + 127) / 128, 256, 0, stream>>>(bufA, W1, b1, bufB);
    k_spmm<<<sb, 256, 0, stream>>>(bufB, rowptr, col, norm_src, norm_dst, bufA);
    k_gemm<<<(N_NODES + 127) / 128, 256, 0, stream>>>(bufA, W2, b2, bufB);

    k_counts<<<nb, 256, 0, stream>>>(gids, cnt);
    int gsb = (((N_NODES + 15) / 16) + 3) / 4;
    k_graphsum<<<gsb, 256, 0, stream>>>(bufB, gids, hg);
    k_mlp<<<NG, 64, 0, stream>>>(hg, cnt, Wm0, bm0, Wm1, bm1, Wm2, bm2, Wm3, bm3, out);
}

// Round 2
// 1335.477 us; speedup vs baseline: 1.3904x; 1.3904x over previous
//
#include <hip/hip_runtime.h>

#define N_NODES 100000
#define N_EDGES 3200000
#define DIM 128
#define NG 64
#define GS_CHUNKS 16

// ---------------- degrees ----------------
__global__ void k_degrees(const int* __restrict__ src, const int* __restrict__ dst,
                          int* __restrict__ degi_out, int* __restrict__ degi_in) {
    int e = blockIdx.x * 256 + threadIdx.x;
    if (e < N_EDGES) {
        atomicAdd(&degi_out[src[e]], 1);
        atomicAdd(&degi_in[dst[e]], 1);
    }
}

// ---------------- norms ----------------
__global__ void k_norms(const int* __restrict__ degi_out, const int* __restrict__ degi_in,
                        float* __restrict__ norm_src, float* __restrict__ norm_dst) {
    int i = blockIdx.x * 256 + threadIdx.x;
    if (i < N_NODES) {
        int a = degi_out[i]; if (a < 1) a = 1;
        int b = degi_in[i];  if (b < 1) b = 1;
        norm_src[i] = rsqrtf((float)a);
        norm_dst[i] = rsqrtf((float)b);
    }
}

// ---------------- exclusive scan of deg_in -> rowptr, cursor (single block) ----------------
__global__ void k_scan(const int* __restrict__ degi_in, int* __restrict__ rowptr,
                       int* __restrict__ cursor) {
    __shared__ int sums[1024];
    int tid = threadIdx.x;
    const int CH = (N_NODES + 1023) / 1024;  // 98
    int beg = tid * CH;
    int end = beg + CH; if (end > N_NODES) end = N_NODES;
    int s = 0;
    for (int i = beg; i < end && i < N_NODES; ++i) s += degi_in[i];
    sums[tid] = s;
    __syncthreads();
    for (int off = 1; off < 1024; off <<= 1) {
        int v = sums[tid];
        int o = (tid >= off) ? sums[tid - off] : 0;
        __syncthreads();
        sums[tid] = v + o;
        __syncthreads();
    }
    int run = (tid > 0) ? sums[tid - 1] : 0;
    for (int i = beg; i < end && i < N_NODES; ++i) {
        rowptr[i] = run; cursor[i] = run; run += degi_in[i];
    }
    if (tid == 1023) rowptr[N_NODES] = sums[1023];
}

// ---------------- CSR fill ----------------
__global__ void k_csr(const int* __restrict__ src, const int* __restrict__ dst,
                      int* __restrict__ cursor, int* __restrict__ col) {
    int e = blockIdx.x * 256 + threadIdx.x;
    if (e < N_EDGES) {
        int d = dst[e];
        int pos = atomicAdd(&cursor[d], 1);
        col[pos] = src[e];
    }
}

// ---------------- SpMM: out[n] = (sum_in-edges in[s]*norm_src[s]) * norm_dst[n] ----------------
__global__ __launch_bounds__(256) void k_spmm(const float* __restrict__ in,
                       const int* __restrict__ rowptr, const int* __restrict__ col,
                       const float* __restrict__ norm_src, const float* __restrict__ norm_dst,
                       float* __restrict__ out) {
    int wave = (blockIdx.x * 256 + threadIdx.x) >> 6;
    int lane = threadIdx.x & 63;
    if (wave >= N_NODES) return;
    int n = wave;
    const float2* in2 = (const float2*)in;
    int jb = rowptr[n], je = rowptr[n + 1];
    float ax = 0.f, ay = 0.f;
    int j = jb;
    for (; j + 4 <= je; j += 4) {
        int s0 = col[j], s1 = col[j + 1], s2 = col[j + 2], s3 = col[j + 3];
        float w0 = norm_src[s0], w1 = norm_src[s1], w2 = norm_src[s2], w3 = norm_src[s3];
        float2 v0 = in2[(size_t)s0 * 64 + lane];
        float2 v1 = in2[(size_t)s1 * 64 + lane];
        float2 v2 = in2[(size_t)s2 * 64 + lane];
        float2 v3 = in2[(size_t)s3 * 64 + lane];
        ax += v0.x * w0; ay += v0.y * w0;
        ax += v1.x * w1; ay += v1.y * w1;
        ax += v2.x * w2; ay += v2.y * w2;
        ax += v3.x * w3; ay += v3.y * w3;
    }
    for (; j < je; ++j) {
        int s = col[j]; float w = norm_src[s];
        float2 v = in2[(size_t)s * 64 + lane];
        ax += v.x * w; ay += v.y * w;
    }
    float nd = norm_dst[n];
    float2* o2 = (float2*)out;
    o2[(size_t)n * 64 + lane] = make_float2(ax * nd, ay * nd);
}

// ---------------- GEMM [N,128] @ [128,128] + bias + relu ----------------
__global__ __launch_bounds__(256) void k_gemm(const float* __restrict__ A,
                      const float* __restrict__ W, const float* __restrict__ bias,
                      float* __restrict__ out) {
    __shared__ float Wl[DIM * DIM];  // 64 KB
    int tid = threadIdx.x;
    for (int i = tid * 4; i < DIM * DIM; i += 256 * 4) {
        *(float4*)&Wl[i] = *(const float4*)&W[i];
    }
    __syncthreads();
    int r0 = blockIdx.x * 128 + (tid >> 4) * 8;
    int c0 = (tid & 15) * 8;
    float bb[8];
    #pragma unroll
    for (int j = 0; j < 8; j++) bb[j] = bias[c0 + j];
    float acc[8][8];
    #pragma unroll
    for (int i = 0; i < 8; i++)
        #pragma unroll
        for (int j = 0; j < 8; j++) acc[i][j] = 0.f;

    for (int k = 0; k < DIM; k += 4) {
        float4 a[8];
        #pragma unroll
        for (int i = 0; i < 8; i++) {
            int r = r0 + i; if (r >= N_NODES) r = N_NODES - 1;
            a[i] = *(const float4*)&A[(size_t)r * DIM + k];
        }
        #pragma unroll
        for (int kk = 0; kk < 4; kk++) {
            float w[8];
            #pragma unroll
            for (int j = 0; j < 8; j++) w[j] = Wl[(k + kk) * DIM + c0 + j];
            #pragma unroll
            for (int i = 0; i < 8; i++) {
                float av = (kk == 0) ? a[i].x : (kk == 1) ? a[i].y : (kk == 2) ? a[i].z : a[i].w;
                #pragma unroll
                for (int j = 0; j < 8; j++) acc[i][j] += av * w[j];
            }
        }
    }
    #pragma unroll
    for (int i = 0; i < 8; i++) {
        int r = r0 + i;
        if (r < N_NODES) {
            float4 o0, o1;
            o0.x = fmaxf(acc[i][0] + bb[0], 0.f);
            o0.y = fmaxf(acc[i][1] + bb[1], 0.f);
            o0.z = fmaxf(acc[i][2] + bb[2], 0.f);
            o0.w = fmaxf(acc[i][3] + bb[3], 0.f);
            o1.x = fmaxf(acc[i][4] + bb[4], 0.f);
            o1.y = fmaxf(acc[i][5] + bb[5], 0.f);
            o1.z = fmaxf(acc[i][6] + bb[6], 0.f);
            o1.w = fmaxf(acc[i][7] + bb[7], 0.f);
            *(float4*)&out[(size_t)r * DIM + c0] = o0;
            *(float4*)&out[(size_t)r * DIM + c0 + 4] = o1;
        }
    }
}

// ---------------- per-graph node ranges via binary search (gids sorted) ----------------
__global__ void k_bounds(const int* __restrict__ gids, int* __restrict__ gstart,
                         int* __restrict__ gend) {
    int g = threadIdx.x;  // 64 threads, one per graph
    if (g >= NG) return;
    // lower bound: first index with gids[i] >= g
    int lo = 0, hi = N_NODES;
    while (lo < hi) { int mid = (lo + hi) >> 1; if (gids[mid] < g) lo = mid + 1; else hi = mid; }
    int s = lo;
    // upper bound: first index with gids[i] > g
    lo = 0; hi = N_NODES;
    while (lo < hi) { int mid = (lo + hi) >> 1; if (gids[mid] <= g) lo = mid + 1; else hi = mid; }
    gstart[g] = s;
    gend[g] = lo;
}

// ---------------- per-graph partial feature sums (no atomics) ----------------
// grid: (NG, GS_CHUNKS); block: 256 threads (2 rows x 128 cols)
__global__ __launch_bounds__(256) void k_graphsum_part(const float* __restrict__ h,
                           const int* __restrict__ gstart, const int* __restrict__ gend,
                           float* __restrict__ partial) {
    __shared__ float red[256];
    int g = blockIdx.x;
    int c = blockIdx.y;
    int f = threadIdx.x & 127;
    int r = threadIdx.x >> 7;  // 0 or 1
    int s = gstart[g], e = gend[g];
    int len = e - s;
    int clen = (len + GS_CHUNKS - 1) / GS_CHUNKS;
    int b0 = s + c * clen;
    int b1 = b0 + clen; if (b1 > e) b1 = e;
    float acc = 0.f;
    for (int nd = b0 + r; nd < b1; nd += 2)
        acc += h[(size_t)nd * DIM + f];
    red[threadIdx.x] = acc;
    __syncthreads();
    if (threadIdx.x < 128)
        partial[((size_t)g * GS_CHUNKS + c) * DIM + threadIdx.x] =
            red[threadIdx.x] + red[threadIdx.x + 128];
}

// ---------------- combine partials -> per-graph mean ----------------
__global__ void k_graphsum_combine(const float* __restrict__ partial,
                                   const int* __restrict__ gstart, const int* __restrict__ gend,
                                   float* __restrict__ hg) {
    int g = blockIdx.x;
    int f = threadIdx.x;  // 128 threads
    float acc = 0.f;
    #pragma unroll
    for (int c = 0; c < GS_CHUNKS; c++)
        acc += partial[((size_t)g * GS_CHUNKS + c) * DIM + f];
    int cntv = gend[g] - gstart[g]; if (cntv < 1) cntv = 1;
    hg[g * DIM + f] = acc / (float)cntv;
}

// ---------------- MLP readout, one wave per graph (hg is already the mean) ----------------
__global__ void k_mlp(const float* __restrict__ hg,
                      const float* __restrict__ Wm0, const float* __restrict__ bm0,
                      const float* __restrict__ Wm1, const float* __restrict__ bm1,
                      const float* __restrict__ Wm2, const float* __restrict__ bm2,
                      const float* __restrict__ Wm3, const float* __restrict__ bm3,
                      float* __restrict__ out) {
    __shared__ float hb[DIM];
    __shared__ float l0[64];
    __shared__ float l1[32];
    __shared__ float l2[16];
    int g = blockIdx.x;
    int t = threadIdx.x;  // 64 threads = 1 wave
    hb[t] = hg[g * DIM + t];
    hb[t + 64] = hg[g * DIM + t + 64];
    __syncthreads();
    {
        float acc = bm0[t];
        for (int k = 0; k < 128; k++) acc += hb[k] * Wm0[k * 64 + t];
        l0[t] = fmaxf(acc, 0.f);
    }
    __syncthreads();
    if (t < 32) {
        float acc = bm1[t];
        for (int k = 0; k < 64; k++) acc += l0[k] * Wm1[k * 32 + t];
        l1[t] = fmaxf(acc, 0.f);
    }
    __syncthreads();
    if (t < 16) {
        float acc = bm2[t];
        for (int k = 0; k < 32; k++) acc += l1[k] * Wm2[k * 16 + t];
        l2[t] = fmaxf(acc, 0.f);
    }
    __syncthreads();
    if (t == 0) {
        float acc = bm3[0];
        for (int k = 0; k < 16; k++) acc += l2[k] * Wm3[k];
        out[g] = acc;
    }
}

extern "C" void kernel_launch(void* const* d_in, const int* in_sizes, int n_in,
                              void* d_out, int out_size, void* d_ws, size_t ws_size,
                              hipStream_t stream) {
    const float* feat = (const float*)d_in[0];
    const int*   src  = (const int*)d_in[1];
    const int*   dst  = (const int*)d_in[2];
    const int*   gids = (const int*)d_in[3];
    const float* W1   = (const float*)d_in[5];
    const float* b1   = (const float*)d_in[6];
    const float* W2   = (const float*)d_in[7];
    const float* b2   = (const float*)d_in[8];
    const float* Wm0  = (const float*)d_in[9];
    const float* bm0  = (const float*)d_in[10];
    const float* Wm1  = (const float*)d_in[11];
    const float* bm1  = (const float*)d_in[12];
    const float* Wm2  = (const float*)d_in[13];
    const float* bm2  = (const float*)d_in[14];
    const float* Wm3  = (const float*)d_in[15];
    const float* bm3  = (const float*)d_in[16];
    float* out = (float*)d_out;

    char* ws = (char*)d_ws;
    size_t off = 0;
    auto alloc = [&](size_t bytes) -> void* {
        void* p = ws + off;
        off += (bytes + 511) & ~(size_t)511;
        return p;
    };
    float* norm_src = (float*)alloc((size_t)N_NODES * 4);
    float* norm_dst = (float*)alloc((size_t)N_NODES * 4);
    int* degi_out = (int*)alloc((size_t)N_NODES * 4);
    int* degi_in  = (int*)alloc((size_t)N_NODES * 4);
    int* rowptr   = (int*)alloc((size_t)(N_NODES + 1) * 4);
    int* cursor   = (int*)alloc((size_t)N_NODES * 4);
    int* col      = (int*)alloc((size_t)N_EDGES * 4);
    float* bufA   = (float*)alloc((size_t)N_NODES * DIM * 4);
    float* bufB   = (float*)alloc((size_t)N_NODES * DIM * 4);
    float* hg     = (float*)alloc((size_t)NG * DIM * 4);
    float* partial = (float*)alloc((size_t)NG * GS_CHUNKS * DIM * 4);
    int* gstart   = (int*)alloc((size_t)NG * 4);
    int* gend     = (int*)alloc((size_t)NG * 4);

    hipMemsetAsync(degi_out, 0, (size_t)N_NODES * 4, stream);
    hipMemsetAsync(degi_in, 0, (size_t)N_NODES * 4, stream);

    int eb = (N_EDGES + 255) / 256;
    int nb = (N_NODES + 255) / 256;
    k_degrees<<<eb, 256, 0, stream>>>(src, dst, degi_out, degi_in);
    k_norms<<<nb, 256, 0, stream>>>(degi_out, degi_in, norm_src, norm_dst);
    k_scan<<<1, 1024, 0, stream>>>(degi_in, rowptr, cursor);
    k_csr<<<eb, 256, 0, stream>>>(src, dst, cursor, col);

    int sb = (N_NODES + 3) / 4;  // 4 waves per 256-thread block, 1 wave per node
    k_spmm<<<sb, 256, 0, stream>>>(feat, rowptr, col, norm_src, norm_dst, bufA);
    k_gemm<<<(N_NODES + 127) / 128, 256, 0, stream>>>(bufA, W1, b1, bufB);
    k_spmm<<<sb, 256, 0, stream>>>(bufB, rowptr, col, norm_src, norm_dst, bufA);
    k_gemm<<<(N_NODES + 127) / 128, 256, 0, stream>>>(bufA, W2, b2, bufB);

    k_bounds<<<1, 64, 0, stream>>>(gids, gstart, gend);
    dim3 gsg(NG, GS_CHUNKS);
    k_graphsum_part<<<gsg, 256, 0, stream>>>(bufB, gstart, gend, partial);
    k_graphsum_combine<<<NG, 128, 0, stream>>>(partial, gstart, gend, hg);
    k_mlp<<<NG, 64, 0, stream>>>(hg, Wm0, bm0, Wm1, bm1, Wm2, bm2, Wm3, bm3, out);
}

// Round 3
// 971.833 us; speedup vs baseline: 1.9106x; 1.3742x over previous
//
#include <hip/hip_runtime.h>

#define N_NODES 100000
#define N_EDGES 3200000
#define DIM 128
#define NG 64
#define GS_CHUNKS 16

#define KSH 9
#define BKT 512
#define NBKT ((N_NODES + BKT - 1) / BKT)      // 196
#define CHUNK 8192
#define NBLK ((N_EDGES + CHUNK - 1) / CHUNK)  // 391

// ---------------- coarse histograms (dst-key for CSR, src-key for out-degree) ----------------
__global__ __launch_bounds__(256) void k_hist1(const int* __restrict__ src, const int* __restrict__ dst,
                                               int* __restrict__ histD, int* __restrict__ histS) {
    __shared__ int hD[NBKT];
    __shared__ int hS[NBKT];
    int t = threadIdx.x, blk = blockIdx.x;
    for (int i = t; i < NBKT; i += 256) { hD[i] = 0; hS[i] = 0; }
    __syncthreads();
    int base = blk * CHUNK;
    for (int i = t; i < CHUNK; i += 256) {
        int e = base + i;
        if (e < N_EDGES) {
            atomicAdd(&hD[dst[e] >> KSH], 1);
            atomicAdd(&hS[src[e] >> KSH], 1);
        }
    }
    __syncthreads();
    for (int i = t; i < NBKT; i += 256) {
        histD[i * NBLK + blk] = hD[i];
        histS[i * NBLK + blk] = hS[i];
    }
}

// ---------------- in-place exclusive scan of NBKT*NBLK ints (single block) ----------------
__global__ void k_scan_arr(int* __restrict__ a) {
    __shared__ int sums[1024];
    const int n = NBKT * NBLK;
    int tid = threadIdx.x;
    const int CH = (n + 1023) / 1024;
    int beg = tid * CH;
    int end = beg + CH; if (end > n) end = n;
    int s = 0;
    for (int i = beg; i < end; i++) s += a[i];
    sums[tid] = s;
    __syncthreads();
    for (int off = 1; off < 1024; off <<= 1) {
        int v = sums[tid];
        int o = (tid >= off) ? sums[tid - off] : 0;
        __syncthreads();
        sums[tid] = v + o;
        __syncthreads();
    }
    int run = (tid > 0) ? sums[tid - 1] : 0;
    for (int i = beg; i < end; i++) { int v = a[i]; a[i] = run; run += v; }
}

// ---------------- scatter edges into coarse buckets (LDS cursors, no global atomics) ----------------
__global__ __launch_bounds__(256) void k_scatter1(const int* __restrict__ src, const int* __restrict__ dst,
                                                  const int* __restrict__ histD, const int* __restrict__ histS,
                                                  int* __restrict__ bufD, int* __restrict__ bufS) {
    __shared__ int cD[NBKT];
    __shared__ int cS[NBKT];
    int t = threadIdx.x, blk = blockIdx.x;
    for (int i = t; i < NBKT; i += 256) {
        cD[i] = histD[i * NBLK + blk];
        cS[i] = histS[i * NBLK + blk];
    }
    __syncthreads();
    int base = blk * CHUNK;
    for (int i = t; i < CHUNK; i += 256) {
        int e = base + i;
        if (e < N_EDGES) {
            int s = src[e], d = dst[e];
            int pD = atomicAdd(&cD[d >> KSH], 1);
            bufD[pD] = ((d & (BKT - 1)) << 17) | s;   // 9-bit local dst | 17-bit src
            int pS = atomicAdd(&cS[s >> KSH], 1);
            bufS[pS] = s & (BKT - 1);                 // 9-bit local src
        }
    }
}

// ---------------- per-bucket fine histogram of src keys -> norm_src ----------------
__global__ __launch_bounds__(256) void k_pass2s(const int* __restrict__ bufS,
                                                const int* __restrict__ histS,
                                                float* __restrict__ norm_src) {
    __shared__ int binc[BKT];
    int b = blockIdx.x, t = threadIdx.x;
    int start = histS[b * NBLK];
    int end = (b + 1 < NBKT) ? histS[(b + 1) * NBLK] : N_EDGES;
    for (int i = t; i < BKT; i += 256) binc[i] = 0;
    __syncthreads();
    for (int i = start + t; i < end; i += 256) atomicAdd(&binc[bufS[i]], 1);
    __syncthreads();
    int nb = N_NODES - b * BKT; if (nb > BKT) nb = BKT;
    for (int j = t; j < nb; j += 256) {
        int c = binc[j]; if (c < 1) c = 1;
        norm_src[b * BKT + j] = rsqrtf((float)c);
    }
}

// ---------------- per-bucket fine sort: rowptr, norm_dst, col ----------------
__global__ __launch_bounds__(256) void k_pass2(const int* __restrict__ bufD,
                                               const int* __restrict__ histD,
                                               int* __restrict__ rowptr, float* __restrict__ norm_dst,
                                               int* __restrict__ col) {
    __shared__ int binc[BKT];
    __shared__ int binoff[BKT];
    int b = blockIdx.x, t = threadIdx.x;
    int start = histD[b * NBLK];
    int end = (b + 1 < NBKT) ? histD[(b + 1) * NBLK] : N_EDGES;
    for (int i = t; i < BKT; i += 256) binc[i] = 0;
    __syncthreads();
    for (int i = start + t; i < end; i += 256) atomicAdd(&binc[bufD[i] >> 17], 1);
    __syncthreads();
    if (t == 0) {
        int run = 0;
        for (int j = 0; j < BKT; j++) { binoff[j] = run; run += binc[j]; }
    }
    __syncthreads();
    int nb = N_NODES - b * BKT; if (nb > BKT) nb = BKT;
    for (int j = t; j < nb; j += 256) {
        rowptr[b * BKT + j] = start + binoff[j];
        int c = binc[j]; if (c < 1) c = 1;
        norm_dst[b * BKT + j] = rsqrtf((float)c);
    }
    if (b == NBKT - 1 && t == 0) rowptr[N_NODES] = N_EDGES;
    __syncthreads();
    // reuse binc as cursors
    for (int i = t; i < BKT; i += 256) binc[i] = binoff[i];
    __syncthreads();
    for (int i = start + t; i < end; i += 256) {
        int v = bufD[i];
        int ld = v >> 17, s = v & 0x1FFFF;
        int p = atomicAdd(&binc[ld], 1);
        col[start + p] = s;
    }
}

// ---------------- SpMM: out[n] = (sum_in-edges in[s]*norm_src[s]) * norm_dst[n] ----------------
__global__ __launch_bounds__(256) void k_spmm(const float* __restrict__ in,
                       const int* __restrict__ rowptr, const int* __restrict__ col,
                       const float* __restrict__ norm_src, const float* __restrict__ norm_dst,
                       float* __restrict__ out) {
    int wave = (blockIdx.x * 256 + threadIdx.x) >> 6;
    int lane = threadIdx.x & 63;
    if (wave >= N_NODES) return;
    int n = wave;
    const float2* in2 = (const float2*)in;
    int jb = rowptr[n], je = rowptr[n + 1];
    float ax = 0.f, ay = 0.f;
    int j = jb;
    for (; j + 4 <= je; j += 4) {
        int s0 = col[j], s1 = col[j + 1], s2 = col[j + 2], s3 = col[j + 3];
        float w0 = norm_src[s0], w1 = norm_src[s1], w2 = norm_src[s2], w3 = norm_src[s3];
        float2 v0 = in2[(size_t)s0 * 64 + lane];
        float2 v1 = in2[(size_t)s1 * 64 + lane];
        float2 v2 = in2[(size_t)s2 * 64 + lane];
        float2 v3 = in2[(size_t)s3 * 64 + lane];
        ax += v0.x * w0; ay += v0.y * w0;
        ax += v1.x * w1; ay += v1.y * w1;
        ax += v2.x * w2; ay += v2.y * w2;
        ax += v3.x * w3; ay += v3.y * w3;
    }
    for (; j < je; ++j) {
        int s = col[j]; float w = norm_src[s];
        float2 v = in2[(size_t)s * 64 + lane];
        ax += v.x * w; ay += v.y * w;
    }
    float nd = norm_dst[n];
    float2* o2 = (float2*)out;
    o2[(size_t)n * 64 + lane] = make_float2(ax * nd, ay * nd);
}

// ---------------- GEMM [N,128] @ [128,128] + bias + relu ----------------
__global__ __launch_bounds__(256) void k_gemm(const float* __restrict__ A,
                      const float* __restrict__ W, const float* __restrict__ bias,
                      float* __restrict__ out) {
    __shared__ float Wl[DIM * DIM];  // 64 KB
    int tid = threadIdx.x;
    for (int i = tid * 4; i < DIM * DIM; i += 256 * 4) {
        *(float4*)&Wl[i] = *(const float4*)&W[i];
    }
    __syncthreads();
    int r0 = blockIdx.x * 128 + (tid >> 4) * 8;
    int c0 = (tid & 15) * 8;
    float bb[8];
    #pragma unroll
    for (int j = 0; j < 8; j++) bb[j] = bias[c0 + j];
    float acc[8][8];
    #pragma unroll
    for (int i = 0; i < 8; i++)
        #pragma unroll
        for (int j = 0; j < 8; j++) acc[i][j] = 0.f;

    for (int k = 0; k < DIM; k += 4) {
        float4 a[8];
        #pragma unroll
        for (int i = 0; i < 8; i++) {
            int r = r0 + i; if (r >= N_NODES) r = N_NODES - 1;
            a[i] = *(const float4*)&A[(size_t)r * DIM + k];
        }
        #pragma unroll
        for (int kk = 0; kk < 4; kk++) {
            float w[8];
            #pragma unroll
            for (int j = 0; j < 8; j++) w[j] = Wl[(k + kk) * DIM + c0 + j];
            #pragma unroll
            for (int i = 0; i < 8; i++) {
                float av = (kk == 0) ? a[i].x : (kk == 1) ? a[i].y : (kk == 2) ? a[i].z : a[i].w;
                #pragma unroll
                for (int j = 0; j < 8; j++) acc[i][j] += av * w[j];
            }
        }
    }
    #pragma unroll
    for (int i = 0; i < 8; i++) {
        int r = r0 + i;
        if (r < N_NODES) {
            float4 o0, o1;
            o0.x = fmaxf(acc[i][0] + bb[0], 0.f);
            o0.y = fmaxf(acc[i][1] + bb[1], 0.f);
            o0.z = fmaxf(acc[i][2] + bb[2], 0.f);
            o0.w = fmaxf(acc[i][3] + bb[3], 0.f);
            o1.x = fmaxf(acc[i][4] + bb[4], 0.f);
            o1.y = fmaxf(acc[i][5] + bb[5], 0.f);
            o1.z = fmaxf(acc[i][6] + bb[6], 0.f);
            o1.w = fmaxf(acc[i][7] + bb[7], 0.f);
            *(float4*)&out[(size_t)r * DIM + c0] = o0;
            *(float4*)&out[(size_t)r * DIM + c0 + 4] = o1;
        }
    }
}

// ---------------- per-graph node ranges via binary search (gids sorted) ----------------
__global__ void k_bounds(const int* __restrict__ gids, int* __restrict__ gstart,
                         int* __restrict__ gend) {
    int g = threadIdx.x;
    if (g >= NG) return;
    int lo = 0, hi = N_NODES;
    while (lo < hi) { int mid = (lo + hi) >> 1; if (gids[mid] < g) lo = mid + 1; else hi = mid; }
    int s = lo;
    lo = 0; hi = N_NODES;
    while (lo < hi) { int mid = (lo + hi) >> 1; if (gids[mid] <= g) lo = mid + 1; else hi = mid; }
    gstart[g] = s;
    gend[g] = lo;
}

// ---------------- per-graph partial feature sums (no atomics) ----------------
__global__ __launch_bounds__(256) void k_graphsum_part(const float* __restrict__ h,
                           const int* __restrict__ gstart, const int* __restrict__ gend,
                           float* __restrict__ partial) {
    __shared__ float red[256];
    int g = blockIdx.x;
    int c = blockIdx.y;
    int f = threadIdx.x & 127;
    int r = threadIdx.x >> 7;
    int s = gstart[g], e = gend[g];
    int len = e - s;
    int clen = (len + GS_CHUNKS - 1) / GS_CHUNKS;
    int b0 = s + c * clen;
    int b1 = b0 + clen; if (b1 > e) b1 = e;
    float acc = 0.f;
    for (int nd = b0 + r; nd < b1; nd += 2)
        acc += h[(size_t)nd * DIM + f];
    red[threadIdx.x] = acc;
    __syncthreads();
    if (threadIdx.x < 128)
        partial[((size_t)g * GS_CHUNKS + c) * DIM + threadIdx.x] =
            red[threadIdx.x] + red[threadIdx.x + 128];
}

// ---------------- combine partials -> per-graph mean ----------------
__global__ void k_graphsum_combine(const float* __restrict__ partial,
                                   const int* __restrict__ gstart, const int* __restrict__ gend,
                                   float* __restrict__ hg) {
    int g = blockIdx.x;
    int f = threadIdx.x;
    float acc = 0.f;
    #pragma unroll
    for (int c = 0; c < GS_CHUNKS; c++)
        acc += partial[((size_t)g * GS_CHUNKS + c) * DIM + f];
    int cntv = gend[g] - gstart[g]; if (cntv < 1) cntv = 1;
    hg[g * DIM + f] = acc / (float)cntv;
}

// ---------------- MLP readout ----------------
__global__ void k_mlp(const float* __restrict__ hg,
                      const float* __restrict__ Wm0, const float* __restrict__ bm0,
                      const float* __restrict__ Wm1, const float* __restrict__ bm1,
                      const float* __restrict__ Wm2, const float* __restrict__ bm2,
                      const float* __restrict__ Wm3, const float* __restrict__ bm3,
                      float* __restrict__ out) {
    __shared__ float hb[DIM];
    __shared__ float l0[64];
    __shared__ float l1[32];
    __shared__ float l2[16];
    int g = blockIdx.x;
    int t = threadIdx.x;
    hb[t] = hg[g * DIM + t];
    hb[t + 64] = hg[g * DIM + t + 64];
    __syncthreads();
    {
        float acc = bm0[t];
        for (int k = 0; k < 128; k++) acc += hb[k] * Wm0[k * 64 + t];
        l0[t] = fmaxf(acc, 0.f);
    }
    __syncthreads();
    if (t < 32) {
        float acc = bm1[t];
        for (int k = 0; k < 64; k++) acc += l0[k] * Wm1[k * 32 + t];
        l1[t] = fmaxf(acc, 0.f);
    }
    __syncthreads();
    if (t < 16) {
        float acc = bm2[t];
        for (int k = 0; k < 32; k++) acc += l1[k] * Wm2[k * 16 + t];
        l2[t] = fmaxf(acc, 0.f);
    }
    __syncthreads();
    if (t == 0) {
        float acc = bm3[0];
        for (int k = 0; k < 16; k++) acc += l2[k] * Wm3[k];
        out[g] = acc;
    }
}

extern "C" void kernel_launch(void* const* d_in, const int* in_sizes, int n_in,
                              void* d_out, int out_size, void* d_ws, size_t ws_size,
                              hipStream_t stream) {
    const float* feat = (const float*)d_in[0];
    const int*   src  = (const int*)d_in[1];
    const int*   dst  = (const int*)d_in[2];
    const int*   gids = (const int*)d_in[3];
    const float* W1   = (const float*)d_in[5];
    const float* b1   = (const float*)d_in[6];
    const float* W2   = (const float*)d_in[7];
    const float* b2   = (const float*)d_in[8];
    const float* Wm0  = (const float*)d_in[9];
    const float* bm0  = (const float*)d_in[10];
    const float* Wm1  = (const float*)d_in[11];
    const float* bm1  = (const float*)d_in[12];
    const float* Wm2  = (const float*)d_in[13];
    const float* bm2  = (const float*)d_in[14];
    const float* Wm3  = (const float*)d_in[15];
    const float* bm3  = (const float*)d_in[16];
    float* out = (float*)d_out;

    char* ws = (char*)d_ws;
    size_t off = 0;
    auto alloc = [&](size_t bytes) -> void* {
        void* p = ws + off;
        off += (bytes + 511) & ~(size_t)511;
        return p;
    };
    float* norm_src = (float*)alloc((size_t)N_NODES * 4);
    float* norm_dst = (float*)alloc((size_t)N_NODES * 4);
    int* rowptr   = (int*)alloc((size_t)(N_NODES + 1) * 4);
    int* histD    = (int*)alloc((size_t)NBKT * NBLK * 4);
    int* histS    = (int*)alloc((size_t)NBKT * NBLK * 4);
    int* bufD     = (int*)alloc((size_t)N_EDGES * 4);
    int* bufS     = (int*)alloc((size_t)N_EDGES * 4);   // later reused as col
    float* bufA   = (float*)alloc((size_t)N_NODES * DIM * 4);
    float* bufB   = (float*)alloc((size_t)N_NODES * DIM * 4);
    float* hg     = (float*)alloc((size_t)NG * DIM * 4);
    float* partial = (float*)alloc((size_t)NG * GS_CHUNKS * DIM * 4);
    int* gstart   = (int*)alloc((size_t)NG * 4);
    int* gend     = (int*)alloc((size_t)NG * 4);
    int* col = bufS;  // alias: bufS consumed by k_pass2s before k_pass2 writes col

    k_hist1<<<NBLK, 256, 0, stream>>>(src, dst, histD, histS);
    k_scan_arr<<<1, 1024, 0, stream>>>(histD);
    k_scan_arr<<<1, 1024, 0, stream>>>(histS);
    k_scatter1<<<NBLK, 256, 0, stream>>>(src, dst, histD, histS, bufD, bufS);
    k_pass2s<<<NBKT, 256, 0, stream>>>(bufS, histS, norm_src);
    k_pass2<<<NBKT, 256, 0, stream>>>(bufD, histD, rowptr, norm_dst, col);

    int sb = (N_NODES + 3) / 4;  // 4 waves per 256-thread block, 1 wave per node
    k_spmm<<<sb, 256, 0, stream>>>(feat, rowptr, col, norm_src, norm_dst, bufA);
    k_gemm<<<(N_NODES + 127) / 128, 256, 0, stream>>>(bufA, W1, b1, bufB);
    k_spmm<<<sb, 256, 0, stream>>>(bufB, rowptr, col, norm_src, norm_dst, bufA);
    k_gemm<<<(N_NODES + 127) / 128, 256, 0, stream>>>(bufA, W2, b2, bufB);

    k_bounds<<<1, 64, 0, stream>>>(gids, gstart, gend);
    dim3 gsg(NG, GS_CHUNKS);
    k_graphsum_part<<<gsg, 256, 0, stream>>>(bufB, gstart, gend, partial);
    k_graphsum_combine<<<NG, 128, 0, stream>>>(partial, gstart, gend, hg);
    k_mlp<<<NG, 64, 0, stream>>>(hg, Wm0, bm0, Wm1, bm1, Wm2, bm2, Wm3, bm3, out);
}

// Round 4
// 748.076 us; speedup vs baseline: 2.4821x; 1.2991x over previous
//
#include <hip/hip_runtime.h>
#include <hip/hip_fp16.h>

#define N_NODES 100000
#define N_EDGES 3200000
#define DIM 128
#define NG 64
#define GS_CHUNKS 16

#define KSH 9
#define BKT 512
#define NBKT ((N_NODES + BKT - 1) / BKT)      // 196
#define CHUNK 8192
#define NBLK ((N_EDGES + CHUNK - 1) / CHUNK)  // 391

// ---------------- coarse histograms (dst-key for CSR, src-key for out-degree) ----------------
__global__ __launch_bounds__(256) void k_hist1(const int* __restrict__ src, const int* __restrict__ dst,
                                               int* __restrict__ histD, int* __restrict__ histS) {
    __shared__ int hD[NBKT];
    __shared__ int hS[NBKT];
    int t = threadIdx.x, blk = blockIdx.x;
    for (int i = t; i < NBKT; i += 256) { hD[i] = 0; hS[i] = 0; }
    __syncthreads();
    int base = blk * CHUNK;
    for (int i = t; i < CHUNK; i += 256) {
        int e = base + i;
        if (e < N_EDGES) {
            atomicAdd(&hD[dst[e] >> KSH], 1);
            atomicAdd(&hS[src[e] >> KSH], 1);
        }
    }
    __syncthreads();
    for (int i = t; i < NBKT; i += 256) {
        histD[i * NBLK + blk] = hD[i];
        histS[i * NBLK + blk] = hS[i];
    }
}

// ---------------- in-place exclusive scan of NBKT*NBLK ints (single block) ----------------
__global__ void k_scan_arr(int* __restrict__ a) {
    __shared__ int sums[1024];
    const int n = NBKT * NBLK;
    int tid = threadIdx.x;
    const int CH = (n + 1023) / 1024;
    int beg = tid * CH;
    int end = beg + CH; if (end > n) end = n;
    int s = 0;
    for (int i = beg; i < end; i++) s += a[i];
    sums[tid] = s;
    __syncthreads();
    for (int off = 1; off < 1024; off <<= 1) {
        int v = sums[tid];
        int o = (tid >= off) ? sums[tid - off] : 0;
        __syncthreads();
        sums[tid] = v + o;
        __syncthreads();
    }
    int run = (tid > 0) ? sums[tid - 1] : 0;
    for (int i = beg; i < end; i++) { int v = a[i]; a[i] = run; run += v; }
}

// ---------------- scatter edges into coarse buckets (LDS cursors, no global atomics) ----------------
__global__ __launch_bounds__(256) void k_scatter1(const int* __restrict__ src, const int* __restrict__ dst,
                                                  const int* __restrict__ histD, const int* __restrict__ histS,
                                                  int* __restrict__ bufD, unsigned short* __restrict__ bufS) {
    __shared__ int cD[NBKT];
    __shared__ int cS[NBKT];
    int t = threadIdx.x, blk = blockIdx.x;
    for (int i = t; i < NBKT; i += 256) {
        cD[i] = histD[i * NBLK + blk];
        cS[i] = histS[i * NBLK + blk];
    }
    __syncthreads();
    int base = blk * CHUNK;
    for (int i = t; i < CHUNK; i += 256) {
        int e = base + i;
        if (e < N_EDGES) {
            int s = src[e], d = dst[e];
            int pD = atomicAdd(&cD[d >> KSH], 1);
            bufD[pD] = ((d & (BKT - 1)) << 17) | s;   // 9-bit local dst | 17-bit src
            int pS = atomicAdd(&cS[s >> KSH], 1);
            bufS[pS] = (unsigned short)(s & (BKT - 1));
        }
    }
}

// ---------------- per-bucket fine histogram of src keys -> norm_src ----------------
__global__ __launch_bounds__(256) void k_pass2s(const unsigned short* __restrict__ bufS,
                                                const int* __restrict__ histS,
                                                float* __restrict__ norm_src) {
    __shared__ int binc[BKT];
    int b = blockIdx.x, t = threadIdx.x;
    int start = histS[b * NBLK];
    int end = (b + 1 < NBKT) ? histS[(b + 1) * NBLK] : N_EDGES;
    for (int i = t; i < BKT; i += 256) binc[i] = 0;
    __syncthreads();
    for (int i = start + t; i < end; i += 256) atomicAdd(&binc[bufS[i]], 1);
    __syncthreads();
    int nb = N_NODES - b * BKT; if (nb > BKT) nb = BKT;
    for (int j = t; j < nb; j += 256) {
        int c = binc[j]; if (c < 1) c = 1;
        norm_src[b * BKT + j] = rsqrtf((float)c);
    }
}

// ---------------- per-bucket fine sort: rowptr, norm_dst, col ----------------
__global__ __launch_bounds__(256) void k_pass2(const int* __restrict__ bufD,
                                               const int* __restrict__ histD,
                                               int* __restrict__ rowptr, float* __restrict__ norm_dst,
                                               int* __restrict__ col) {
    __shared__ int binc[BKT];
    __shared__ int binoff[BKT];
    int b = blockIdx.x, t = threadIdx.x;
    int start = histD[b * NBLK];
    int end = (b + 1 < NBKT) ? histD[(b + 1) * NBLK] : N_EDGES;
    for (int i = t; i < BKT; i += 256) binc[i] = 0;
    __syncthreads();
    for (int i = start + t; i < end; i += 256) atomicAdd(&binc[bufD[i] >> 17], 1);
    __syncthreads();
    // exclusive scan of binc[512] -> binoff, done by wave 0 (64 lanes x 8 bins)
    if (t < 64) {
        int base8 = t * 8;
        int loc[8]; int s8 = 0;
        #pragma unroll
        for (int k = 0; k < 8; k++) { loc[k] = s8; s8 += binc[base8 + k]; }
        int x = s8;
        #pragma unroll
        for (int off = 1; off < 64; off <<= 1) {
            int y = __shfl_up(x, off);
            if (t >= off) x += y;
        }
        int excl = x - s8;
        #pragma unroll
        for (int k = 0; k < 8; k++) binoff[base8 + k] = excl + loc[k];
    }
    __syncthreads();
    int nb = N_NODES - b * BKT; if (nb > BKT) nb = BKT;
    for (int j = t; j < nb; j += 256) {
        rowptr[b * BKT + j] = start + binoff[j];
        int c = binc[j]; if (c < 1) c = 1;
        norm_dst[b * BKT + j] = rsqrtf((float)c);
    }
    if (b == NBKT - 1 && t == 0) rowptr[N_NODES] = N_EDGES;
    __syncthreads();
    // reuse binc as cursors
    for (int i = t; i < BKT; i += 256) binc[i] = binoff[i];
    __syncthreads();
    for (int i = start + t; i < end; i += 256) {
        int v = bufD[i];
        int ld = v >> 17, s = v & 0x1FFFF;
        int p = atomicAdd(&binc[ld], 1);
        col[start + p] = s;
    }
}

// ---------------- cast fp32 features -> fp16 pre-scaled by norm_src ----------------
__global__ __launch_bounds__(256) void k_cast(const float* __restrict__ in,
                                              const float* __restrict__ norm_src,
                                              __half2* __restrict__ out) {
    int i4 = blockIdx.x * 256 + threadIdx.x;          // one float4 per thread
    const int TOT = N_NODES * DIM / 4;
    if (i4 >= TOT) return;
    int row = i4 >> 5;                                // 32 float4 per row
    float sc = norm_src[row];
    float4 v = ((const float4*)in)[i4];
    out[2 * i4]     = __floats2half2_rn(v.x * sc, v.y * sc);
    out[2 * i4 + 1] = __floats2half2_rn(v.z * sc, v.w * sc);
}

// ---------------- SpMM (fp16 gather): out[n] = (sum in16[s]) * norm_dst[n] ----------------
// in16 rows are pre-scaled by norm_src.
__global__ __launch_bounds__(256) void k_spmm16(const __half2* __restrict__ in,
                       const int* __restrict__ rowptr, const int* __restrict__ col,
                       const float* __restrict__ norm_dst, float* __restrict__ out) {
    int wave = (blockIdx.x * 256 + threadIdx.x) >> 6;
    int lane = threadIdx.x & 63;
    if (wave >= N_NODES) return;
    int jb = rowptr[wave], je = rowptr[wave + 1];
    float ax = 0.f, ay = 0.f;
    int j = jb;
    for (; j + 8 <= je; j += 8) {
        int s0 = col[j], s1 = col[j+1], s2 = col[j+2], s3 = col[j+3];
        int s4 = col[j+4], s5 = col[j+5], s6 = col[j+6], s7 = col[j+7];
        __half2 v0 = in[(size_t)s0 * 64 + lane];
        __half2 v1 = in[(size_t)s1 * 64 + lane];
        __half2 v2 = in[(size_t)s2 * 64 + lane];
        __half2 v3 = in[(size_t)s3 * 64 + lane];
        __half2 v4 = in[(size_t)s4 * 64 + lane];
        __half2 v5 = in[(size_t)s5 * 64 + lane];
        __half2 v6 = in[(size_t)s6 * 64 + lane];
        __half2 v7 = in[(size_t)s7 * 64 + lane];
        float2 f;
        f = __half22float2(v0); ax += f.x; ay += f.y;
        f = __half22float2(v1); ax += f.x; ay += f.y;
        f = __half22float2(v2); ax += f.x; ay += f.y;
        f = __half22float2(v3); ax += f.x; ay += f.y;
        f = __half22float2(v4); ax += f.x; ay += f.y;
        f = __half22float2(v5); ax += f.x; ay += f.y;
        f = __half22float2(v6); ax += f.x; ay += f.y;
        f = __half22float2(v7); ax += f.x; ay += f.y;
    }
    for (; j < je; ++j) {
        float2 f = __half22float2(in[(size_t)col[j] * 64 + lane]);
        ax += f.x; ay += f.y;
    }
    float nd = norm_dst[wave];
    ((float2*)out)[(size_t)wave * 64 + lane] = make_float2(ax * nd, ay * nd);
}

// ---------------- GEMM [N,128] @ [128,128] + bias + relu (+optional row scale), fp16 out ----------------
template <bool SCALE>
__global__ __launch_bounds__(256) void k_gemm16(const float* __restrict__ A,
                      const float* __restrict__ W, const float* __restrict__ bias,
                      const float* __restrict__ rowscale, __half* __restrict__ out) {
    __shared__ float Wl[DIM * DIM];  // 64 KB
    int tid = threadIdx.x;
    for (int i = tid * 4; i < DIM * DIM; i += 256 * 4) {
        *(float4*)&Wl[i] = *(const float4*)&W[i];
    }
    __syncthreads();
    int r0 = blockIdx.x * 128 + (tid >> 4) * 8;
    int c0 = (tid & 15) * 8;
    float bb[8];
    #pragma unroll
    for (int j = 0; j < 8; j++) bb[j] = bias[c0 + j];
    float acc[8][8];
    #pragma unroll
    for (int i = 0; i < 8; i++)
        #pragma unroll
        for (int j = 0; j < 8; j++) acc[i][j] = 0.f;

    for (int k = 0; k < DIM; k += 4) {
        float4 a[8];
        #pragma unroll
        for (int i = 0; i < 8; i++) {
            int r = r0 + i; if (r >= N_NODES) r = N_NODES - 1;
            a[i] = *(const float4*)&A[(size_t)r * DIM + k];
        }
        #pragma unroll
        for (int kk = 0; kk < 4; kk++) {
            float w[8];
            #pragma unroll
            for (int j = 0; j < 8; j++) w[j] = Wl[(k + kk) * DIM + c0 + j];
            #pragma unroll
            for (int i = 0; i < 8; i++) {
                float av = (kk == 0) ? a[i].x : (kk == 1) ? a[i].y : (kk == 2) ? a[i].z : a[i].w;
                #pragma unroll
                for (int j = 0; j < 8; j++) acc[i][j] += av * w[j];
            }
        }
    }
    #pragma unroll
    for (int i = 0; i < 8; i++) {
        int r = r0 + i;
        if (r < N_NODES) {
            float sc = 1.f;
            if (SCALE) sc = rowscale[r];
            __half tmp[8];
            #pragma unroll
            for (int j = 0; j < 8; j++)
                tmp[j] = __float2half(fmaxf(acc[i][j] + bb[j], 0.f) * sc);
            *(float4*)&out[(size_t)r * DIM + c0] = *(float4*)tmp;
        }
    }
}

// ---------------- per-graph node ranges via binary search (gids sorted) ----------------
__global__ void k_bounds(const int* __restrict__ gids, int* __restrict__ gstart,
                         int* __restrict__ gend) {
    int g = threadIdx.x;
    if (g >= NG) return;
    int lo = 0, hi = N_NODES;
    while (lo < hi) { int mid = (lo + hi) >> 1; if (gids[mid] < g) lo = mid + 1; else hi = mid; }
    int s = lo;
    lo = 0; hi = N_NODES;
    while (lo < hi) { int mid = (lo + hi) >> 1; if (gids[mid] <= g) lo = mid + 1; else hi = mid; }
    gstart[g] = s;
    gend[g] = lo;
}

// ---------------- per-graph partial feature sums over fp16 h (no atomics) ----------------
__global__ __launch_bounds__(256) void k_graphsum_part(const __half2* __restrict__ h,
                           const int* __restrict__ gstart, const int* __restrict__ gend,
                           float* __restrict__ partial) {
    __shared__ float redx[256];
    __shared__ float redy[256];
    int g = blockIdx.x;
    int c = blockIdx.y;
    int p = threadIdx.x & 63;   // feature pair
    int r = threadIdx.x >> 6;   // 0..3
    int s = gstart[g], e = gend[g];
    int clen = (e - s + GS_CHUNKS - 1) / GS_CHUNKS;
    int b0 = s + c * clen;
    int b1 = b0 + clen; if (b1 > e) b1 = e;
    float ax = 0.f, ay = 0.f;
    for (int nd = b0 + r; nd < b1; nd += 4) {
        float2 f = __half22float2(h[(size_t)nd * 64 + p]);
        ax += f.x; ay += f.y;
    }
    redx[threadIdx.x] = ax; redy[threadIdx.x] = ay;
    __syncthreads();
    if (threadIdx.x < 64) {
        float sx = redx[threadIdx.x] + redx[threadIdx.x + 64] + redx[threadIdx.x + 128] + redx[threadIdx.x + 192];
        float sy = redy[threadIdx.x] + redy[threadIdx.x + 64] + redy[threadIdx.x + 128] + redy[threadIdx.x + 192];
        float* pp = &partial[((size_t)g * GS_CHUNKS + c) * DIM];
        pp[2 * threadIdx.x] = sx;
        pp[2 * threadIdx.x + 1] = sy;
    }
}

// ---------------- combine partials -> per-graph mean ----------------
__global__ void k_graphsum_combine(const float* __restrict__ partial,
                                   const int* __restrict__ gstart, const int* __restrict__ gend,
                                   float* __restrict__ hg) {
    int g = blockIdx.x;
    int f = threadIdx.x;
    float acc = 0.f;
    #pragma unroll
    for (int c = 0; c < GS_CHUNKS; c++)
        acc += partial[((size_t)g * GS_CHUNKS + c) * DIM + f];
    int cntv = gend[g] - gstart[g]; if (cntv < 1) cntv = 1;
    hg[g * DIM + f] = acc / (float)cntv;
}

// ---------------- MLP readout ----------------
__global__ void k_mlp(const float* __restrict__ hg,
                      const float* __restrict__ Wm0, const float* __restrict__ bm0,
                      const float* __restrict__ Wm1, const float* __restrict__ bm1,
                      const float* __restrict__ Wm2, const float* __restrict__ bm2,
                      const float* __restrict__ Wm3, const float* __restrict__ bm3,
                      float* __restrict__ out) {
    __shared__ float hb[DIM];
    __shared__ float l0[64];
    __shared__ float l1[32];
    __shared__ float l2[16];
    int g = blockIdx.x;
    int t = threadIdx.x;
    hb[t] = hg[g * DIM + t];
    hb[t + 64] = hg[g * DIM + t + 64];
    __syncthreads();
    {
        float acc = bm0[t];
        for (int k = 0; k < 128; k++) acc += hb[k] * Wm0[k * 64 + t];
        l0[t] = fmaxf(acc, 0.f);
    }
    __syncthreads();
    if (t < 32) {
        float acc = bm1[t];
        for (int k = 0; k < 64; k++) acc += l0[k] * Wm1[k * 32 + t];
        l1[t] = fmaxf(acc, 0.f);
    }
    __syncthreads();
    if (t < 16) {
        float acc = bm2[t];
        for (int k = 0; k < 32; k++) acc += l1[k] * Wm2[k * 16 + t];
        l2[t] = fmaxf(acc, 0.f);
    }
    __syncthreads();
    if (t == 0) {
        float acc = bm3[0];
        for (int k = 0; k < 16; k++) acc += l2[k] * Wm3[k];
        out[g] = acc;
    }
}

extern "C" void kernel_launch(void* const* d_in, const int* in_sizes, int n_in,
                              void* d_out, int out_size, void* d_ws, size_t ws_size,
                              hipStream_t stream) {
    const float* feat = (const float*)d_in[0];
    const int*   src  = (const int*)d_in[1];
    const int*   dst  = (const int*)d_in[2];
    const int*   gids = (const int*)d_in[3];
    const float* W1   = (const float*)d_in[5];
    const float* b1   = (const float*)d_in[6];
    const float* W2   = (const float*)d_in[7];
    const float* b2   = (const float*)d_in[8];
    const float* Wm0  = (const float*)d_in[9];
    const float* bm0  = (const float*)d_in[10];
    const float* Wm1  = (const float*)d_in[11];
    const float* bm1  = (const float*)d_in[12];
    const float* Wm2  = (const float*)d_in[13];
    const float* bm2  = (const float*)d_in[14];
    const float* Wm3  = (const float*)d_in[15];
    const float* bm3  = (const float*)d_in[16];
    float* out = (float*)d_out;

    char* ws = (char*)d_ws;
    size_t off = 0;
    auto alloc = [&](size_t bytes) -> void* {
        void* p = ws + off;
        off += (bytes + 511) & ~(size_t)511;
        return p;
    };
    float* norm_src = (float*)alloc((size_t)N_NODES * 4);
    float* norm_dst = (float*)alloc((size_t)N_NODES * 4);
    int* rowptr   = (int*)alloc((size_t)(N_NODES + 1) * 4);
    int* histD    = (int*)alloc((size_t)NBKT * NBLK * 4);
    int* histS    = (int*)alloc((size_t)NBKT * NBLK * 4);
    int* bufD     = (int*)alloc((size_t)N_EDGES * 4);
    int* colbuf   = (int*)alloc((size_t)N_EDGES * 4);   // bufS (ushort) first, then col (int)
    __half2* feat16 = (__half2*)alloc((size_t)N_NODES * DIM * 2);
    __half* h16   = (__half*)alloc((size_t)N_NODES * DIM * 2);   // layer-1 activations (pre-scaled)
    __half* g16   = (__half*)alloc((size_t)N_NODES * DIM * 2);   // layer-2 activations
    float* bufA   = (float*)alloc((size_t)N_NODES * DIM * 4);    // SpMM fp32 output
    float* hg     = (float*)alloc((size_t)NG * DIM * 4);
    float* partial = (float*)alloc((size_t)NG * GS_CHUNKS * DIM * 4);
    int* gstart   = (int*)alloc((size_t)NG * 4);
    int* gend     = (int*)alloc((size_t)NG * 4);
    unsigned short* bufS = (unsigned short*)colbuf;
    int* col = colbuf;  // k_pass2s consumes bufS before k_pass2 writes col

    k_hist1<<<NBLK, 256, 0, stream>>>(src, dst, histD, histS);
    k_scan_arr<<<1, 1024, 0, stream>>>(histD);
    k_scan_arr<<<1, 1024, 0, stream>>>(histS);
    k_scatter1<<<NBLK, 256, 0, stream>>>(src, dst, histD, histS, bufD, bufS);
    k_pass2s<<<NBKT, 256, 0, stream>>>(bufS, histS, norm_src);
    k_pass2<<<NBKT, 256, 0, stream>>>(bufD, histD, rowptr, norm_dst, col);

    k_cast<<<(N_NODES * DIM / 4 + 255) / 256, 256, 0, stream>>>(feat, norm_src, feat16);

    int sb = (N_NODES + 3) / 4;  // 1 wave per node, 4 waves per block
    k_spmm16<<<sb, 256, 0, stream>>>(feat16, rowptr, col, norm_dst, bufA);
    k_gemm16<true><<<(N_NODES + 127) / 128, 256, 0, stream>>>(bufA, W1, b1, norm_src, h16);
    k_spmm16<<<sb, 256, 0, stream>>>((const __half2*)h16, rowptr, col, norm_dst, bufA);
    k_gemm16<false><<<(N_NODES + 127) / 128, 256, 0, stream>>>(bufA, W2, b2, nullptr, g16);

    k_bounds<<<1, 64, 0, stream>>>(gids, gstart, gend);
    dim3 gsg(NG, GS_CHUNKS);
    k_graphsum_part<<<gsg, 256, 0, stream>>>((const __half2*)g16, gstart, gend, partial);
    k_graphsum_combine<<<NG, 128, 0, stream>>>(partial, gstart, gend, hg);
    k_mlp<<<NG, 64, 0, stream>>>(hg, Wm0, bm0, Wm1, bm1, Wm2, bm2, Wm3, bm3, out);
}

// Round 5
// 509.689 us; speedup vs baseline: 3.6430x; 1.4677x over previous
//
#include <hip/hip_runtime.h>
#include <hip/hip_fp16.h>

#define N_NODES 100000
#define N_EDGES 3200000
#define DIM 128
#define NG 64
#define GS_CHUNKS 16

#define KSH 9
#define BKT 512
#define NBKT ((N_NODES + BKT - 1) / BKT)      // 196
#define CHUNK 8192
#define NBLK ((N_EDGES + CHUNK - 1) / CHUNK)  // 391

// ---------------- coarse histograms (dst-key for CSR, src-key for out-degree) ----------------
__global__ __launch_bounds__(256) void k_hist1(const int* __restrict__ src, const int* __restrict__ dst,
                                               int* __restrict__ histD, int* __restrict__ histS) {
    __shared__ int hD[NBKT];
    __shared__ int hS[NBKT];
    int t = threadIdx.x, blk = blockIdx.x;
    for (int i = t; i < NBKT; i += 256) { hD[i] = 0; hS[i] = 0; }
    __syncthreads();
    int base = blk * CHUNK;
    for (int i = t; i < CHUNK; i += 256) {
        int e = base + i;
        if (e < N_EDGES) {
            atomicAdd(&hD[dst[e] >> KSH], 1);
            atomicAdd(&hS[src[e] >> KSH], 1);
        }
    }
    __syncthreads();
    for (int i = t; i < NBKT; i += 256) {
        histD[i * NBLK + blk] = hD[i];
        histS[i * NBLK + blk] = hS[i];
    }
}

// ---------------- hierarchical exclusive scan of histD & histS (rows = buckets) ----------------
// step 1: per-row totals (392 rows: first NBKT are histD, next NBKT are histS)
__global__ __launch_bounds__(256) void k_rowsum(const int* __restrict__ histD,
                                                const int* __restrict__ histS,
                                                int* __restrict__ rowtot) {
    __shared__ int red[256];
    int r = blockIdx.x;
    const int* a = (r < NBKT) ? (histD + (size_t)r * NBLK) : (histS + (size_t)(r - NBKT) * NBLK);
    int t = threadIdx.x;
    int s = 0;
    for (int i = t; i < NBLK; i += 256) s += a[i];
    red[t] = s;
    __syncthreads();
    for (int off = 128; off > 0; off >>= 1) {
        if (t < off) red[t] += red[t + off];
        __syncthreads();
    }
    if (t == 0) rowtot[r] = red[0];
}

// step 2: two independent exclusive scans over the 196-row totals (in place)
__global__ void k_basescan(int* __restrict__ rowtot) {
    __shared__ int sh[256];
    int t = threadIdx.x;
    int o0 = (t < NBKT) ? rowtot[t] : 0;
    int o1 = (t < NBKT) ? rowtot[NBKT + t] : 0;
    sh[t] = o0; __syncthreads();
    for (int off = 1; off < 256; off <<= 1) {
        int v = sh[t]; int u = (t >= off) ? sh[t - off] : 0;
        __syncthreads(); sh[t] = v + u; __syncthreads();
    }
    int e0 = sh[t] - o0;
    __syncthreads();
    sh[t] = o1; __syncthreads();
    for (int off = 1; off < 256; off <<= 1) {
        int v = sh[t]; int u = (t >= off) ? sh[t - off] : 0;
        __syncthreads(); sh[t] = v + u; __syncthreads();
    }
    int e1 = sh[t] - o1;
    if (t < NBKT) { rowtot[t] = e0; rowtot[NBKT + t] = e1; }
}

// step 3: in-row exclusive scan + row base, in place
__global__ __launch_bounds__(512) void k_rowapply(int* __restrict__ histD, int* __restrict__ histS,
                                                  const int* __restrict__ rowtot) {
    __shared__ int sh[512];
    int r = blockIdx.x;
    int* a = (r < NBKT) ? (histD + (size_t)r * NBLK) : (histS + (size_t)(r - NBKT) * NBLK);
    int t = threadIdx.x;
    int v = (t < NBLK) ? a[t] : 0;
    sh[t] = v; __syncthreads();
    for (int off = 1; off < 512; off <<= 1) {
        int x = sh[t]; int u = (t >= off) ? sh[t - off] : 0;
        __syncthreads(); sh[t] = x + u; __syncthreads();
    }
    int excl = sh[t] - v + rowtot[r];
    if (t < NBLK) a[t] = excl;
}

// ---------------- scatter edges into coarse buckets (LDS cursors, no global atomics) ----------------
__global__ __launch_bounds__(256) void k_scatter1(const int* __restrict__ src, const int* __restrict__ dst,
                                                  const int* __restrict__ histD, const int* __restrict__ histS,
                                                  int* __restrict__ bufD, unsigned short* __restrict__ bufS) {
    __shared__ int cD[NBKT];
    __shared__ int cS[NBKT];
    int t = threadIdx.x, blk = blockIdx.x;
    for (int i = t; i < NBKT; i += 256) {
        cD[i] = histD[i * NBLK + blk];
        cS[i] = histS[i * NBLK + blk];
    }
    __syncthreads();
    int base = blk * CHUNK;
    for (int i = t; i < CHUNK; i += 256) {
        int e = base + i;
        if (e < N_EDGES) {
            int s = src[e], d = dst[e];
            int pD = atomicAdd(&cD[d >> KSH], 1);
            bufD[pD] = ((d & (BKT - 1)) << 17) | s;   // 9-bit local dst | 17-bit src
            int pS = atomicAdd(&cS[s >> KSH], 1);
            bufS[pS] = (unsigned short)(s & (BKT - 1));
        }
    }
}

// ---------------- per-bucket fine histogram of src keys -> norm_src ----------------
__global__ __launch_bounds__(256) void k_pass2s(const unsigned short* __restrict__ bufS,
                                                const int* __restrict__ histS,
                                                float* __restrict__ norm_src) {
    __shared__ int binc[BKT];
    int b = blockIdx.x, t = threadIdx.x;
    int start = histS[b * NBLK];
    int end = (b + 1 < NBKT) ? histS[(b + 1) * NBLK] : N_EDGES;
    for (int i = t; i < BKT; i += 256) binc[i] = 0;
    __syncthreads();
    for (int i = start + t; i < end; i += 256) atomicAdd(&binc[bufS[i]], 1);
    __syncthreads();
    int nb = N_NODES - b * BKT; if (nb > BKT) nb = BKT;
    for (int j = t; j < nb; j += 256) {
        int c = binc[j]; if (c < 1) c = 1;
        norm_src[b * BKT + j] = rsqrtf((float)c);
    }
}

// ---------------- per-bucket fine sort: rowptr, norm_dst, col ----------------
__global__ __launch_bounds__(256) void k_pass2(const int* __restrict__ bufD,
                                               const int* __restrict__ histD,
                                               int* __restrict__ rowptr, float* __restrict__ norm_dst,
                                               int* __restrict__ col) {
    __shared__ int binc[BKT];
    __shared__ int binoff[BKT];
    int b = blockIdx.x, t = threadIdx.x;
    int start = histD[b * NBLK];
    int end = (b + 1 < NBKT) ? histD[(b + 1) * NBLK] : N_EDGES;
    for (int i = t; i < BKT; i += 256) binc[i] = 0;
    __syncthreads();
    for (int i = start + t; i < end; i += 256) atomicAdd(&binc[bufD[i] >> 17], 1);
    __syncthreads();
    // exclusive scan of binc[512] -> binoff, wave 0 (64 lanes x 8 bins)
    if (t < 64) {
        int base8 = t * 8;
        int loc[8]; int s8 = 0;
        #pragma unroll
        for (int k = 0; k < 8; k++) { loc[k] = s8; s8 += binc[base8 + k]; }
        int x = s8;
        #pragma unroll
        for (int off = 1; off < 64; off <<= 1) {
            int y = __shfl_up(x, off);
            if (t >= off) x += y;
        }
        int excl = x - s8;
        #pragma unroll
        for (int k = 0; k < 8; k++) binoff[base8 + k] = excl + loc[k];
    }
    __syncthreads();
    int nb = N_NODES - b * BKT; if (nb > BKT) nb = BKT;
    for (int j = t; j < nb; j += 256) {
        rowptr[b * BKT + j] = start + binoff[j];
        int c = binc[j]; if (c < 1) c = 1;
        norm_dst[b * BKT + j] = rsqrtf((float)c);
    }
    if (b == NBKT - 1 && t == 0) rowptr[N_NODES] = N_EDGES;
    __syncthreads();
    // reuse binc as cursors
    for (int i = t; i < BKT; i += 256) binc[i] = binoff[i];
    __syncthreads();
    for (int i = start + t; i < end; i += 256) {
        int v = bufD[i];
        int ld = v >> 17, s = v & 0x1FFFF;
        int p = atomicAdd(&binc[ld], 1);
        col[start + p] = s;
    }
}

// ---------------- cast fp32 features -> fp16 pre-scaled by norm_src ----------------
__global__ __launch_bounds__(256) void k_cast(const float* __restrict__ in,
                                              const float* __restrict__ norm_src,
                                              __half2* __restrict__ out) {
    int i4 = blockIdx.x * 256 + threadIdx.x;          // one float4 per thread
    const int TOT = N_NODES * DIM / 4;
    if (i4 >= TOT) return;
    int row = i4 >> 5;                                // 32 float4 per row
    float sc = norm_src[row];
    float4 v = ((const float4*)in)[i4];
    out[2 * i4]     = __floats2half2_rn(v.x * sc, v.y * sc);
    out[2 * i4 + 1] = __floats2half2_rn(v.z * sc, v.w * sc);
}

// ---------------- SpMM (fp16 gather): out[n] = (sum in16[s]) * norm_dst[n] ----------------
__global__ __launch_bounds__(256) void k_spmm16(const __half2* __restrict__ in,
                       const int* __restrict__ rowptr, const int* __restrict__ col,
                       const float* __restrict__ norm_dst, float* __restrict__ out) {
    int wave = (blockIdx.x * 256 + threadIdx.x) >> 6;
    int lane = threadIdx.x & 63;
    if (wave >= N_NODES) return;
    int jb = rowptr[wave], je = rowptr[wave + 1];
    float ax = 0.f, ay = 0.f;
    int j = jb;
    for (; j + 8 <= je; j += 8) {
        int s0 = col[j], s1 = col[j+1], s2 = col[j+2], s3 = col[j+3];
        int s4 = col[j+4], s5 = col[j+5], s6 = col[j+6], s7 = col[j+7];
        __half2 v0 = in[(size_t)s0 * 64 + lane];
        __half2 v1 = in[(size_t)s1 * 64 + lane];
        __half2 v2 = in[(size_t)s2 * 64 + lane];
        __half2 v3 = in[(size_t)s3 * 64 + lane];
        __half2 v4 = in[(size_t)s4 * 64 + lane];
        __half2 v5 = in[(size_t)s5 * 64 + lane];
        __half2 v6 = in[(size_t)s6 * 64 + lane];
        __half2 v7 = in[(size_t)s7 * 64 + lane];
        float2 f;
        f = __half22float2(v0); ax += f.x; ay += f.y;
        f = __half22float2(v1); ax += f.x; ay += f.y;
        f = __half22float2(v2); ax += f.x; ay += f.y;
        f = __half22float2(v3); ax += f.x; ay += f.y;
        f = __half22float2(v4); ax += f.x; ay += f.y;
        f = __half22float2(v5); ax += f.x; ay += f.y;
        f = __half22float2(v6); ax += f.x; ay += f.y;
        f = __half22float2(v7); ax += f.x; ay += f.y;
    }
    for (; j < je; ++j) {
        float2 f = __half22float2(in[(size_t)col[j] * 64 + lane]);
        ax += f.x; ay += f.y;
    }
    float nd = norm_dst[wave];
    ((float2*)out)[(size_t)wave * 64 + lane] = make_float2(ax * nd, ay * nd);
}

// ---------------- GEMM [N,128] @ [128,128] + bias + relu (+optional row scale), fp16 out ----------------
template <bool SCALE>
__global__ __launch_bounds__(256) void k_gemm16(const float* __restrict__ A,
                      const float* __restrict__ W, const float* __restrict__ bias,
                      const float* __restrict__ rowscale, __half* __restrict__ out) {
    __shared__ float Wl[DIM * DIM];  // 64 KB
    int tid = threadIdx.x;
    for (int i = tid * 4; i < DIM * DIM; i += 256 * 4) {
        *(float4*)&Wl[i] = *(const float4*)&W[i];
    }
    __syncthreads();
    int r0 = blockIdx.x * 128 + (tid >> 4) * 8;
    int c0 = (tid & 15) * 8;
    float bb[8];
    #pragma unroll
    for (int j = 0; j < 8; j++) bb[j] = bias[c0 + j];
    float acc[8][8];
    #pragma unroll
    for (int i = 0; i < 8; i++)
        #pragma unroll
        for (int j = 0; j < 8; j++) acc[i][j] = 0.f;

    for (int k = 0; k < DIM; k += 4) {
        float4 a[8];
        #pragma unroll
        for (int i = 0; i < 8; i++) {
            int r = r0 + i; if (r >= N_NODES) r = N_NODES - 1;
            a[i] = *(const float4*)&A[(size_t)r * DIM + k];
        }
        #pragma unroll
        for (int kk = 0; kk < 4; kk++) {
            float w[8];
            #pragma unroll
            for (int j = 0; j < 8; j++) w[j] = Wl[(k + kk) * DIM + c0 + j];
            #pragma unroll
            for (int i = 0; i < 8; i++) {
                float av = (kk == 0) ? a[i].x : (kk == 1) ? a[i].y : (kk == 2) ? a[i].z : a[i].w;
                #pragma unroll
                for (int j = 0; j < 8; j++) acc[i][j] += av * w[j];
            }
        }
    }
    #pragma unroll
    for (int i = 0; i < 8; i++) {
        int r = r0 + i;
        if (r < N_NODES) {
            float sc = 1.f;
            if (SCALE) sc = rowscale[r];
            __half tmp[8];
            #pragma unroll
            for (int j = 0; j < 8; j++)
                tmp[j] = __float2half(fmaxf(acc[i][j] + bb[j], 0.f) * sc);
            *(float4*)&out[(size_t)r * DIM + c0] = *(float4*)tmp;
        }
    }
}

// ---------------- per-graph node ranges via binary search (gids sorted) ----------------
__global__ void k_bounds(const int* __restrict__ gids, int* __restrict__ gstart,
                         int* __restrict__ gend) {
    int g = threadIdx.x;
    if (g >= NG) return;
    int lo = 0, hi = N_NODES;
    while (lo < hi) { int mid = (lo + hi) >> 1; if (gids[mid] < g) lo = mid + 1; else hi = mid; }
    int s = lo;
    lo = 0; hi = N_NODES;
    while (lo < hi) { int mid = (lo + hi) >> 1; if (gids[mid] <= g) lo = mid + 1; else hi = mid; }
    gstart[g] = s;
    gend[g] = lo;
}

// ---------------- per-graph partial feature sums over fp16 h (no atomics) ----------------
__global__ __launch_bounds__(256) void k_graphsum_part(const __half2* __restrict__ h,
                           const int* __restrict__ gstart, const int* __restrict__ gend,
                           float* __restrict__ partial) {
    __shared__ float redx[256];
    __shared__ float redy[256];
    int g = blockIdx.x;
    int c = blockIdx.y;
    int p = threadIdx.x & 63;   // feature pair
    int r = threadIdx.x >> 6;   // 0..3
    int s = gstart[g], e = gend[g];
    int clen = (e - s + GS_CHUNKS - 1) / GS_CHUNKS;
    int b0 = s + c * clen;
    int b1 = b0 + clen; if (b1 > e) b1 = e;
    float ax = 0.f, ay = 0.f;
    for (int nd = b0 + r; nd < b1; nd += 4) {
        float2 f = __half22float2(h[(size_t)nd * 64 + p]);
        ax += f.x; ay += f.y;
    }
    redx[threadIdx.x] = ax; redy[threadIdx.x] = ay;
    __syncthreads();
    if (threadIdx.x < 64) {
        float sx = redx[threadIdx.x] + redx[threadIdx.x + 64] + redx[threadIdx.x + 128] + redx[threadIdx.x + 192];
        float sy = redy[threadIdx.x] + redy[threadIdx.x + 64] + redy[threadIdx.x + 128] + redy[threadIdx.x + 192];
        float* pp = &partial[((size_t)g * GS_CHUNKS + c) * DIM];
        pp[2 * threadIdx.x] = sx;
        pp[2 * threadIdx.x + 1] = sy;
    }
}

// ---------------- combine partials -> per-graph mean ----------------
__global__ void k_graphsum_combine(const float* __restrict__ partial,
                                   const int* __restrict__ gstart, const int* __restrict__ gend,
                                   float* __restrict__ hg) {
    int g = blockIdx.x;
    int f = threadIdx.x;
    float acc = 0.f;
    #pragma unroll
    for (int c = 0; c < GS_CHUNKS; c++)
        acc += partial[((size_t)g * GS_CHUNKS + c) * DIM + f];
    int cntv = gend[g] - gstart[g]; if (cntv < 1) cntv = 1;
    hg[g * DIM + f] = acc / (float)cntv;
}

// ---------------- MLP readout ----------------
__global__ void k_mlp(const float* __restrict__ hg,
                      const float* __restrict__ Wm0, const float* __restrict__ bm0,
                      const float* __restrict__ Wm1, const float* __restrict__ bm1,
                      const float* __restrict__ Wm2, const float* __restrict__ bm2,
                      const float* __restrict__ Wm3, const float* __restrict__ bm3,
                      float* __restrict__ out) {
    __shared__ float hb[DIM];
    __shared__ float l0[64];
    __shared__ float l1[32];
    __shared__ float l2[16];
    int g = blockIdx.x;
    int t = threadIdx.x;
    hb[t] = hg[g * DIM + t];
    hb[t + 64] = hg[g * DIM + t + 64];
    __syncthreads();
    {
        float acc = bm0[t];
        for (int k = 0; k < 128; k++) acc += hb[k] * Wm0[k * 64 + t];
        l0[t] = fmaxf(acc, 0.f);
    }
    __syncthreads();
    if (t < 32) {
        float acc = bm1[t];
        for (int k = 0; k < 64; k++) acc += l0[k] * Wm1[k * 32 + t];
        l1[t] = fmaxf(acc, 0.f);
    }
    __syncthreads();
    if (t < 16) {
        float acc = bm2[t];
        for (int k = 0; k < 32; k++) acc += l1[k] * Wm2[k * 16 + t];
        l2[t] = fmaxf(acc, 0.f);
    }
    __syncthreads();
    if (t == 0) {
        float acc = bm3[0];
        for (int k = 0; k < 16; k++) acc += l2[k] * Wm3[k];
        out[g] = acc;
    }
}

extern "C" void kernel_launch(void* const* d_in, const int* in_sizes, int n_in,
                              void* d_out, int out_size, void* d_ws, size_t ws_size,
                              hipStream_t stream) {
    const float* feat = (const float*)d_in[0];
    const int*   src  = (const int*)d_in[1];
    const int*   dst  = (const int*)d_in[2];
    const int*   gids = (const int*)d_in[3];
    const float* W1   = (const float*)d_in[5];
    const float* b1   = (const float*)d_in[6];
    const float* W2   = (const float*)d_in[7];
    const float* b2   = (const float*)d_in[8];
    const float* Wm0  = (const float*)d_in[9];
    const float* bm0  = (const float*)d_in[10];
    const float* Wm1  = (const float*)d_in[11];
    const float* bm1  = (const float*)d_in[12];
    const float* Wm2  = (const float*)d_in[13];
    const float* bm2  = (const float*)d_in[14];
    const float* Wm3  = (const float*)d_in[15];
    const float* bm3  = (const float*)d_in[16];
    float* out = (float*)d_out;

    char* ws = (char*)d_ws;
    size_t off = 0;
    auto alloc = [&](size_t bytes) -> void* {
        void* p = ws + off;
        off += (bytes + 511) & ~(size_t)511;
        return p;
    };
    float* norm_src = (float*)alloc((size_t)N_NODES * 4);
    float* norm_dst = (float*)alloc((size_t)N_NODES * 4);
    int* rowptr   = (int*)alloc((size_t)(N_NODES + 1) * 4);
    int* histD    = (int*)alloc((size_t)NBKT * NBLK * 4);
    int* histS    = (int*)alloc((size_t)NBKT * NBLK * 4);
    int* rowtot   = (int*)alloc((size_t)(2 * NBKT) * 4);
    int* bufD     = (int*)alloc((size_t)N_EDGES * 4);
    int* colbuf   = (int*)alloc((size_t)N_EDGES * 4);   // bufS (ushort) first, then col (int)
    __half2* feat16 = (__half2*)alloc((size_t)N_NODES * DIM * 2);
    __half* h16   = (__half*)alloc((size_t)N_NODES * DIM * 2);
    __half* g16   = (__half*)alloc((size_t)N_NODES * DIM * 2);
    float* bufA   = (float*)alloc((size_t)N_NODES * DIM * 4);
    float* hg     = (float*)alloc((size_t)NG * DIM * 4);
    float* partial = (float*)alloc((size_t)NG * GS_CHUNKS * DIM * 4);
    int* gstart   = (int*)alloc((size_t)NG * 4);
    int* gend     = (int*)alloc((size_t)NG * 4);
    unsigned short* bufS = (unsigned short*)colbuf;
    int* col = colbuf;  // k_pass2s consumes bufS before k_pass2 writes col

    k_hist1<<<NBLK, 256, 0, stream>>>(src, dst, histD, histS);
    k_rowsum<<<2 * NBKT, 256, 0, stream>>>(histD, histS, rowtot);
    k_basescan<<<1, 256, 0, stream>>>(rowtot);
    k_rowapply<<<2 * NBKT, 512, 0, stream>>>(histD, histS, rowtot);
    k_scatter1<<<NBLK, 256, 0, stream>>>(src, dst, histD, histS, bufD, bufS);
    k_pass2s<<<NBKT, 256, 0, stream>>>(bufS, histS, norm_src);
    k_pass2<<<NBKT, 256, 0, stream>>>(bufD, histD, rowptr, norm_dst, col);

    k_cast<<<(N_NODES * DIM / 4 + 255) / 256, 256, 0, stream>>>(feat, norm_src, feat16);

    int sb = (N_NODES + 3) / 4;  // 1 wave per node, 4 waves per block
    k_spmm16<<<sb, 256, 0, stream>>>(feat16, rowptr, col, norm_dst, bufA);
    k_gemm16<true><<<(N_NODES + 127) / 128, 256, 0, stream>>>(bufA, W1, b1, norm_src, h16);
    k_spmm16<<<sb, 256, 0, stream>>>((const __half2*)h16, rowptr, col, norm_dst, bufA);
    k_gemm16<false><<<(N_NODES + 127) / 128, 256, 0, stream>>>(bufA, W2, b2, nullptr, g16);

    k_bounds<<<1, 64, 0, stream>>>(gids, gstart, gend);
    dim3 gsg(NG, GS_CHUNKS);
    k_graphsum_part<<<gsg, 256, 0, stream>>>((const __half2*)g16, gstart, gend, partial);
    k_graphsum_combine<<<NG, 128, 0, stream>>>(partial, gstart, gend, hg);
    k_mlp<<<NG, 64, 0, stream>>>(hg, Wm0, bm0, Wm1, bm1, Wm2, bm2, Wm3, bm3, out);
}

// Round 6
// 448.764 us; speedup vs baseline: 4.1376x; 1.1358x over previous
//
#include <hip/hip_runtime.h>
#include <hip/hip_fp16.h>

#define N_NODES 100000
#define N_EDGES 3200000
#define DIM 128
#define NG 64
#define GS_CHUNKS 16

#define KSH 9
#define BKT 512
#define NBKT ((N_NODES + BKT - 1) / BKT)      // 196
#define CHUNK 8192
#define NBLK ((N_EDGES + CHUNK - 1) / CHUNK)  // 391

using f16x8 = __attribute__((ext_vector_type(8))) _Float16;
using f32x4 = __attribute__((ext_vector_type(4))) float;

// ---------------- coarse histograms (dst-key for CSR, src-key for out-degree) ----------------
__global__ __launch_bounds__(256) void k_hist1(const int* __restrict__ src, const int* __restrict__ dst,
                                               int* __restrict__ histD, int* __restrict__ histS) {
    __shared__ int hD[NBKT];
    __shared__ int hS[NBKT];
    int t = threadIdx.x, blk = blockIdx.x;
    for (int i = t; i < NBKT; i += 256) { hD[i] = 0; hS[i] = 0; }
    __syncthreads();
    int base = blk * CHUNK;
    for (int i = t; i < CHUNK; i += 256) {
        int e = base + i;
        if (e < N_EDGES) {
            atomicAdd(&hD[dst[e] >> KSH], 1);
            atomicAdd(&hS[src[e] >> KSH], 1);
        }
    }
    __syncthreads();
    for (int i = t; i < NBKT; i += 256) {
        histD[i * NBLK + blk] = hD[i];
        histS[i * NBLK + blk] = hS[i];
    }
}

// ---------------- hierarchical exclusive scan of histD & histS ----------------
__global__ __launch_bounds__(256) void k_rowsum(const int* __restrict__ histD,
                                                const int* __restrict__ histS,
                                                int* __restrict__ rowtot) {
    __shared__ int red[256];
    int r = blockIdx.x;
    const int* a = (r < NBKT) ? (histD + (size_t)r * NBLK) : (histS + (size_t)(r - NBKT) * NBLK);
    int t = threadIdx.x;
    int s = 0;
    for (int i = t; i < NBLK; i += 256) s += a[i];
    red[t] = s;
    __syncthreads();
    for (int off = 128; off > 0; off >>= 1) {
        if (t < off) red[t] += red[t + off];
        __syncthreads();
    }
    if (t == 0) rowtot[r] = red[0];
}

__global__ void k_basescan(int* __restrict__ rowtot) {
    __shared__ int sh[256];
    int t = threadIdx.x;
    int o0 = (t < NBKT) ? rowtot[t] : 0;
    int o1 = (t < NBKT) ? rowtot[NBKT + t] : 0;
    sh[t] = o0; __syncthreads();
    for (int off = 1; off < 256; off <<= 1) {
        int v = sh[t]; int u = (t >= off) ? sh[t - off] : 0;
        __syncthreads(); sh[t] = v + u; __syncthreads();
    }
    int e0 = sh[t] - o0;
    __syncthreads();
    sh[t] = o1; __syncthreads();
    for (int off = 1; off < 256; off <<= 1) {
        int v = sh[t]; int u = (t >= off) ? sh[t - off] : 0;
        __syncthreads(); sh[t] = v + u; __syncthreads();
    }
    int e1 = sh[t] - o1;
    if (t < NBKT) { rowtot[t] = e0; rowtot[NBKT + t] = e1; }
}

__global__ __launch_bounds__(512) void k_rowapply(int* __restrict__ histD, int* __restrict__ histS,
                                                  const int* __restrict__ rowtot) {
    __shared__ int sh[512];
    int r = blockIdx.x;
    int* a = (r < NBKT) ? (histD + (size_t)r * NBLK) : (histS + (size_t)(r - NBKT) * NBLK);
    int t = threadIdx.x;
    int v = (t < NBLK) ? a[t] : 0;
    sh[t] = v; __syncthreads();
    for (int off = 1; off < 512; off <<= 1) {
        int x = sh[t]; int u = (t >= off) ? sh[t - off] : 0;
        __syncthreads(); sh[t] = x + u; __syncthreads();
    }
    int excl = sh[t] - v + rowtot[r];
    if (t < NBLK) a[t] = excl;
}

// ---------------- scatter edges into coarse buckets ----------------
__global__ __launch_bounds__(256) void k_scatter1(const int* __restrict__ src, const int* __restrict__ dst,
                                                  const int* __restrict__ histD, const int* __restrict__ histS,
                                                  int* __restrict__ bufD, unsigned short* __restrict__ bufS) {
    __shared__ int cD[NBKT];
    __shared__ int cS[NBKT];
    int t = threadIdx.x, blk = blockIdx.x;
    for (int i = t; i < NBKT; i += 256) {
        cD[i] = histD[i * NBLK + blk];
        cS[i] = histS[i * NBLK + blk];
    }
    __syncthreads();
    int base = blk * CHUNK;
    for (int i = t; i < CHUNK; i += 256) {
        int e = base + i;
        if (e < N_EDGES) {
            int s = src[e], d = dst[e];
            int pD = atomicAdd(&cD[d >> KSH], 1);
            bufD[pD] = ((d & (BKT - 1)) << 17) | s;
            int pS = atomicAdd(&cS[s >> KSH], 1);
            bufS[pS] = (unsigned short)(s & (BKT - 1));
        }
    }
}

// ---------------- per-bucket fine histogram of src keys -> norm_src ----------------
__global__ __launch_bounds__(256) void k_pass2s(const unsigned short* __restrict__ bufS,
                                                const int* __restrict__ histS,
                                                float* __restrict__ norm_src) {
    __shared__ int binc[BKT];
    int b = blockIdx.x, t = threadIdx.x;
    int start = histS[b * NBLK];
    int end = (b + 1 < NBKT) ? histS[(b + 1) * NBLK] : N_EDGES;
    for (int i = t; i < BKT; i += 256) binc[i] = 0;
    __syncthreads();
    for (int i = start + t; i < end; i += 256) atomicAdd(&binc[bufS[i]], 1);
    __syncthreads();
    int nb = N_NODES - b * BKT; if (nb > BKT) nb = BKT;
    for (int j = t; j < nb; j += 256) {
        int c = binc[j]; if (c < 1) c = 1;
        norm_src[b * BKT + j] = rsqrtf((float)c);
    }
}

// ---------------- per-bucket fine sort: rowptr, norm_dst, col ----------------
__global__ __launch_bounds__(256) void k_pass2(const int* __restrict__ bufD,
                                               const int* __restrict__ histD,
                                               int* __restrict__ rowptr, float* __restrict__ norm_dst,
                                               int* __restrict__ col) {
    __shared__ int binc[BKT];
    __shared__ int binoff[BKT];
    int b = blockIdx.x, t = threadIdx.x;
    int start = histD[b * NBLK];
    int end = (b + 1 < NBKT) ? histD[(b + 1) * NBLK] : N_EDGES;
    for (int i = t; i < BKT; i += 256) binc[i] = 0;
    __syncthreads();
    for (int i = start + t; i < end; i += 256) atomicAdd(&binc[bufD[i] >> 17], 1);
    __syncthreads();
    if (t < 64) {
        int base8 = t * 8;
        int loc[8]; int s8 = 0;
        #pragma unroll
        for (int k = 0; k < 8; k++) { loc[k] = s8; s8 += binc[base8 + k]; }
        int x = s8;
        #pragma unroll
        for (int off = 1; off < 64; off <<= 1) {
            int y = __shfl_up(x, off);
            if (t >= off) x += y;
        }
        int excl = x - s8;
        #pragma unroll
        for (int k = 0; k < 8; k++) binoff[base8 + k] = excl + loc[k];
    }
    __syncthreads();
    int nb = N_NODES - b * BKT; if (nb > BKT) nb = BKT;
    for (int j = t; j < nb; j += 256) {
        rowptr[b * BKT + j] = start + binoff[j];
        int c = binc[j]; if (c < 1) c = 1;
        norm_dst[b * BKT + j] = rsqrtf((float)c);
    }
    if (b == NBKT - 1 && t == 0) rowptr[N_NODES] = N_EDGES;
    __syncthreads();
    for (int i = t; i < BKT; i += 256) binc[i] = binoff[i];
    __syncthreads();
    for (int i = start + t; i < end; i += 256) {
        int v = bufD[i];
        int ld = v >> 17, s = v & 0x1FFFF;
        int p = atomicAdd(&binc[ld], 1);
        col[start + p] = s;
    }
}

// ---------------- cast fp32 features -> fp16 pre-scaled by norm_src ----------------
__global__ __launch_bounds__(256) void k_cast(const float* __restrict__ in,
                                              const float* __restrict__ norm_src,
                                              __half2* __restrict__ out) {
    int i4 = blockIdx.x * 256 + threadIdx.x;
    const int TOT = N_NODES * DIM / 4;
    if (i4 >= TOT) return;
    int row = i4 >> 5;
    float sc = norm_src[row];
    float4 v = ((const float4*)in)[i4];
    out[2 * i4]     = __floats2half2_rn(v.x * sc, v.y * sc);
    out[2 * i4 + 1] = __floats2half2_rn(v.z * sc, v.w * sc);
}

// ---------------- SpMM (fp16 gather, 2 rows per wave-load): out16[n] = (sum in16[s]) * nd ----------------
// lanes 0-31 handle even edges, lanes 32-63 odd edges; each lane loads 8 B (4 cols).
__global__ __launch_bounds__(256) void k_spmm16(const __half2* __restrict__ in,
                       const int* __restrict__ rowptr, const int* __restrict__ col,
                       const float* __restrict__ norm_dst, __half2* __restrict__ out) {
    int wave = (blockIdx.x * 256 + threadIdx.x) >> 6;
    int lane = threadIdx.x & 63;
    if (wave >= N_NODES) return;
    int jb = rowptr[wave], je = rowptr[wave + 1];
    int half = lane >> 5, l32 = lane & 31;
    float a0 = 0.f, a1 = 0.f, a2 = 0.f, a3 = 0.f;
    int j = jb;
    for (; j + 8 <= je; j += 8) {
        int sa = col[j + half];
        int sb = col[j + 2 + half];
        int sc = col[j + 4 + half];
        int sd = col[j + 6 + half];
        uint2 ra = *(const uint2*)&in[(size_t)sa * 64 + 2 * l32];
        uint2 rb = *(const uint2*)&in[(size_t)sb * 64 + 2 * l32];
        uint2 rc = *(const uint2*)&in[(size_t)sc * 64 + 2 * l32];
        uint2 rd = *(const uint2*)&in[(size_t)sd * 64 + 2 * l32];
        float2 f;
        f = __half22float2(*(__half2*)&ra.x); a0 += f.x; a1 += f.y;
        f = __half22float2(*(__half2*)&ra.y); a2 += f.x; a3 += f.y;
        f = __half22float2(*(__half2*)&rb.x); a0 += f.x; a1 += f.y;
        f = __half22float2(*(__half2*)&rb.y); a2 += f.x; a3 += f.y;
        f = __half22float2(*(__half2*)&rc.x); a0 += f.x; a1 += f.y;
        f = __half22float2(*(__half2*)&rc.y); a2 += f.x; a3 += f.y;
        f = __half22float2(*(__half2*)&rd.x); a0 += f.x; a1 += f.y;
        f = __half22float2(*(__half2*)&rd.y); a2 += f.x; a3 += f.y;
    }
    for (; j + 2 <= je; j += 2) {
        int s = col[j + half];
        uint2 r = *(const uint2*)&in[(size_t)s * 64 + 2 * l32];
        float2 f;
        f = __half22float2(*(__half2*)&r.x); a0 += f.x; a1 += f.y;
        f = __half22float2(*(__half2*)&r.y); a2 += f.x; a3 += f.y;
    }
    if (j < je && half == 0) {
        int s = col[j];
        uint2 r = *(const uint2*)&in[(size_t)s * 64 + 2 * l32];
        float2 f;
        f = __half22float2(*(__half2*)&r.x); a0 += f.x; a1 += f.y;
        f = __half22float2(*(__half2*)&r.y); a2 += f.x; a3 += f.y;
    }
    a0 += __shfl_xor(a0, 32);
    a1 += __shfl_xor(a1, 32);
    a2 += __shfl_xor(a2, 32);
    a3 += __shfl_xor(a3, 32);
    if (half == 0) {
        float nd = norm_dst[wave];
        __half2 o0 = __floats2half2_rn(a0 * nd, a1 * nd);
        __half2 o1 = __floats2half2_rn(a2 * nd, a3 * nd);
        uint2 o;
        o.x = *(unsigned*)&o0;
        o.y = *(unsigned*)&o1;
        *(uint2*)&out[(size_t)wave * 64 + 2 * l32] = o;
    }
}

// ---------------- MFMA GEMM: [N,128]f16 @ [128,128] + bias, relu, (opt rowscale), fp16 out ----------------
// Each block = 4 waves; wave handles a 16-row strip x all 128 cols via 8x 16x16 tiles.
// A-frag (16x16x32 f16): lane l -> row l&15, k = (l>>4)*8 + i. C/D: col = l&15, row = (l>>4)*4 + r.
template <bool SCALE>
__global__ __launch_bounds__(256) void k_gemm_mfma(const __half* __restrict__ A,
        const float* __restrict__ W, const float* __restrict__ bias,
        const float* __restrict__ rowscale, __half* __restrict__ out) {
    __shared__ _Float16 lds[128 * 136];   // W^T padded (+8 f16/row); reused for C repack
    int tid = threadIdx.x;
    // stage W transposed: lds[n*136 + k] = W[k*128+n]
    for (int idx = tid * 4; idx < DIM * DIM; idx += 256 * 4) {
        int k = idx >> 7, n = idx & 127;
        float4 w = *(const float4*)&W[idx];
        lds[(n + 0) * 136 + k] = (_Float16)w.x;
        lds[(n + 1) * 136 + k] = (_Float16)w.y;
        lds[(n + 2) * 136 + k] = (_Float16)w.z;
        lds[(n + 3) * 136 + k] = (_Float16)w.w;
    }
    __syncthreads();
    int wv = tid >> 6, lane = tid & 63;
    int rbase = blockIdx.x * 64 + wv * 16;
    int l15 = lane & 15, kg = lane >> 4;
    int arow = rbase + l15; if (arow >= N_NODES) arow = N_NODES - 1;
    const _Float16* Af = (const _Float16*)A + (size_t)arow * DIM + kg * 8;
    f16x8 a0 = *(const f16x8*)(Af + 0);
    f16x8 a1 = *(const f16x8*)(Af + 32);
    f16x8 a2 = *(const f16x8*)(Af + 64);
    f16x8 a3 = *(const f16x8*)(Af + 96);
    f32x4 acc[8];
    #pragma unroll
    for (int nt = 0; nt < 8; nt++) acc[nt] = (f32x4){0.f, 0.f, 0.f, 0.f};
    #pragma unroll
    for (int nt = 0; nt < 8; nt++) {
        const _Float16* bb = &lds[(nt * 16 + l15) * 136 + kg * 8];
        f16x8 b0 = *(const f16x8*)(bb + 0);
        f16x8 b1 = *(const f16x8*)(bb + 32);
        f16x8 b2 = *(const f16x8*)(bb + 64);
        f16x8 b3 = *(const f16x8*)(bb + 96);
        acc[nt] = __builtin_amdgcn_mfma_f32_16x16x32_f16(a0, b0, acc[nt], 0, 0, 0);
        acc[nt] = __builtin_amdgcn_mfma_f32_16x16x32_f16(a1, b1, acc[nt], 0, 0, 0);
        acc[nt] = __builtin_amdgcn_mfma_f32_16x16x32_f16(a2, b2, acc[nt], 0, 0, 0);
        acc[nt] = __builtin_amdgcn_mfma_f32_16x16x32_f16(a3, b3, acc[nt], 0, 0, 0);
    }
    __syncthreads();   // W^T no longer needed; reuse lds for C repack
    float bsc[4];
    #pragma unroll
    for (int r = 0; r < 4; r++) {
        if (SCALE) {
            int row = rbase + kg * 4 + r; if (row >= N_NODES) row = N_NODES - 1;
            bsc[r] = rowscale[row];
        } else bsc[r] = 1.f;
    }
    #pragma unroll
    for (int nt = 0; nt < 8; nt++) {
        float bv = bias[nt * 16 + l15];
        #pragma unroll
        for (int r = 0; r < 4; r++) {
            float v = fmaxf(acc[nt][r] + bv, 0.f) * bsc[r];
            lds[(size_t)(wv * 16 + kg * 4 + r) * 136 + nt * 16 + l15] = (_Float16)v;
        }
    }
    __syncthreads();
    _Float16* o16 = (_Float16*)out;
    #pragma unroll
    for (int t = 0; t < 4; t++) {
        int lrow = wv * 16 + t * 4 + kg;
        int grow = rbase + t * 4 + kg;
        f16x8 v = *(const f16x8*)&lds[(size_t)lrow * 136 + l15 * 8];
        if (grow < N_NODES)
            *(f16x8*)&o16[(size_t)grow * DIM + l15 * 8] = v;
    }
}

// ---------------- per-graph node ranges via binary search (gids sorted) ----------------
__global__ void k_bounds(const int* __restrict__ gids, int* __restrict__ gstart,
                         int* __restrict__ gend) {
    int g = threadIdx.x;
    if (g >= NG) return;
    int lo = 0, hi = N_NODES;
    while (lo < hi) { int mid = (lo + hi) >> 1; if (gids[mid] < g) lo = mid + 1; else hi = mid; }
    int s = lo;
    lo = 0; hi = N_NODES;
    while (lo < hi) { int mid = (lo + hi) >> 1; if (gids[mid] <= g) lo = mid + 1; else hi = mid; }
    gstart[g] = s;
    gend[g] = lo;
}

// ---------------- per-graph partial feature sums over fp16 h ----------------
__global__ __launch_bounds__(256) void k_graphsum_part(const __half2* __restrict__ h,
                           const int* __restrict__ gstart, const int* __restrict__ gend,
                           float* __restrict__ partial) {
    __shared__ float redx[256];
    __shared__ float redy[256];
    int g = blockIdx.x;
    int c = blockIdx.y;
    int p = threadIdx.x & 63;
    int r = threadIdx.x >> 6;
    int s = gstart[g], e = gend[g];
    int clen = (e - s + GS_CHUNKS - 1) / GS_CHUNKS;
    int b0 = s + c * clen;
    int b1 = b0 + clen; if (b1 > e) b1 = e;
    float ax = 0.f, ay = 0.f;
    for (int nd = b0 + r; nd < b1; nd += 4) {
        float2 f = __half22float2(h[(size_t)nd * 64 + p]);
        ax += f.x; ay += f.y;
    }
    redx[threadIdx.x] = ax; redy[threadIdx.x] = ay;
    __syncthreads();
    if (threadIdx.x < 64) {
        float sx = redx[threadIdx.x] + redx[threadIdx.x + 64] + redx[threadIdx.x + 128] + redx[threadIdx.x + 192];
        float sy = redy[threadIdx.x] + redy[threadIdx.x + 64] + redy[threadIdx.x + 128] + redy[threadIdx.x + 192];
        float* pp = &partial[((size_t)g * GS_CHUNKS + c) * DIM];
        pp[2 * threadIdx.x] = sx;
        pp[2 * threadIdx.x + 1] = sy;
    }
}

// ---------------- combine partials -> per-graph mean ----------------
__global__ void k_graphsum_combine(const float* __restrict__ partial,
                                   const int* __restrict__ gstart, const int* __restrict__ gend,
                                   float* __restrict__ hg) {
    int g = blockIdx.x;
    int f = threadIdx.x;
    float acc = 0.f;
    #pragma unroll
    for (int c = 0; c < GS_CHUNKS; c++)
        acc += partial[((size_t)g * GS_CHUNKS + c) * DIM + f];
    int cntv = gend[g] - gstart[g]; if (cntv < 1) cntv = 1;
    hg[g * DIM + f] = acc / (float)cntv;
}

// ---------------- MLP readout ----------------
__global__ void k_mlp(const float* __restrict__ hg,
                      const float* __restrict__ Wm0, const float* __restrict__ bm0,
                      const float* __restrict__ Wm1, const float* __restrict__ bm1,
                      const float* __restrict__ Wm2, const float* __restrict__ bm2,
                      const float* __restrict__ Wm3, const float* __restrict__ bm3,
                      float* __restrict__ out) {
    __shared__ float hb[DIM];
    __shared__ float l0[64];
    __shared__ float l1[32];
    __shared__ float l2[16];
    int g = blockIdx.x;
    int t = threadIdx.x;
    hb[t] = hg[g * DIM + t];
    hb[t + 64] = hg[g * DIM + t + 64];
    __syncthreads();
    {
        float acc = bm0[t];
        for (int k = 0; k < 128; k++) acc += hb[k] * Wm0[k * 64 + t];
        l0[t] = fmaxf(acc, 0.f);
    }
    __syncthreads();
    if (t < 32) {
        float acc = bm1[t];
        for (int k = 0; k < 64; k++) acc += l0[k] * Wm1[k * 32 + t];
        l1[t] = fmaxf(acc, 0.f);
    }
    __syncthreads();
    if (t < 16) {
        float acc = bm2[t];
        for (int k = 0; k < 32; k++) acc += l1[k] * Wm2[k * 16 + t];
        l2[t] = fmaxf(acc, 0.f);
    }
    __syncthreads();
    if (t == 0) {
        float acc = bm3[0];
        for (int k = 0; k < 16; k++) acc += l2[k] * Wm3[k];
        out[g] = acc;
    }
}

extern "C" void kernel_launch(void* const* d_in, const int* in_sizes, int n_in,
                              void* d_out, int out_size, void* d_ws, size_t ws_size,
                              hipStream_t stream) {
    const float* feat = (const float*)d_in[0];
    const int*   src  = (const int*)d_in[1];
    const int*   dst  = (const int*)d_in[2];
    const int*   gids = (const int*)d_in[3];
    const float* W1   = (const float*)d_in[5];
    const float* b1   = (const float*)d_in[6];
    const float* W2   = (const float*)d_in[7];
    const float* b2   = (const float*)d_in[8];
    const float* Wm0  = (const float*)d_in[9];
    const float* bm0  = (const float*)d_in[10];
    const float* Wm1  = (const float*)d_in[11];
    const float* bm1  = (const float*)d_in[12];
    const float* Wm2  = (const float*)d_in[13];
    const float* bm2  = (const float*)d_in[14];
    const float* Wm3  = (const float*)d_in[15];
    const float* bm3  = (const float*)d_in[16];
    float* out = (float*)d_out;

    char* ws = (char*)d_ws;
    size_t off = 0;
    auto alloc = [&](size_t bytes) -> void* {
        void* p = ws + off;
        off += (bytes + 511) & ~(size_t)511;
        return p;
    };
    float* norm_src = (float*)alloc((size_t)N_NODES * 4);
    float* norm_dst = (float*)alloc((size_t)N_NODES * 4);
    int* rowptr   = (int*)alloc((size_t)(N_NODES + 1) * 4);
    int* histD    = (int*)alloc((size_t)NBKT * NBLK * 4);
    int* histS    = (int*)alloc((size_t)NBKT * NBLK * 4);
    int* rowtot   = (int*)alloc((size_t)(2 * NBKT) * 4);
    int* bufD     = (int*)alloc((size_t)N_EDGES * 4);
    int* colbuf   = (int*)alloc((size_t)N_EDGES * 4);   // bufS (ushort) first, then col (int)
    __half2* feat16 = (__half2*)alloc((size_t)N_NODES * DIM * 2);
    __half* s16   = (__half*)alloc((size_t)N_NODES * DIM * 2);   // SpMM output (fp16)
    __half* h16   = (__half*)alloc((size_t)N_NODES * DIM * 2);   // gemm1 output (pre-scaled)
    __half* g16   = (__half*)alloc((size_t)N_NODES * DIM * 2);   // gemm2 output
    float* hg     = (float*)alloc((size_t)NG * DIM * 4);
    float* partial = (float*)alloc((size_t)NG * GS_CHUNKS * DIM * 4);
    int* gstart   = (int*)alloc((size_t)NG * 4);
    int* gend     = (int*)alloc((size_t)NG * 4);
    unsigned short* bufS = (unsigned short*)colbuf;
    int* col = colbuf;  // k_pass2s consumes bufS before k_pass2 writes col

    k_hist1<<<NBLK, 256, 0, stream>>>(src, dst, histD, histS);
    k_rowsum<<<2 * NBKT, 256, 0, stream>>>(histD, histS, rowtot);
    k_basescan<<<1, 256, 0, stream>>>(rowtot);
    k_rowapply<<<2 * NBKT, 512, 0, stream>>>(histD, histS, rowtot);
    k_scatter1<<<NBLK, 256, 0, stream>>>(src, dst, histD, histS, bufD, bufS);
    k_pass2s<<<NBKT, 256, 0, stream>>>(bufS, histS, norm_src);
    k_pass2<<<NBKT, 256, 0, stream>>>(bufD, histD, rowptr, norm_dst, col);

    k_cast<<<(N_NODES * DIM / 4 + 255) / 256, 256, 0, stream>>>(feat, norm_src, feat16);

    int sb = (N_NODES + 3) / 4;  // 1 wave per node, 4 waves per block
    int gb = (N_NODES + 63) / 64;
    k_spmm16<<<sb, 256, 0, stream>>>(feat16, rowptr, col, norm_dst, (__half2*)s16);
    k_gemm_mfma<true><<<gb, 256, 0, stream>>>(s16, W1, b1, norm_src, h16);
    k_spmm16<<<sb, 256, 0, stream>>>((const __half2*)h16, rowptr, col, norm_dst, (__half2*)s16);
    k_gemm_mfma<false><<<gb, 256, 0, stream>>>(s16, W2, b2, nullptr, g16);

    k_bounds<<<1, 64, 0, stream>>>(gids, gstart, gend);
    dim3 gsg(NG, GS_CHUNKS);
    k_graphsum_part<<<gsg, 256, 0, stream>>>((const __half2*)g16, gstart, gend, partial);
    k_graphsum_combine<<<NG, 128, 0, stream>>>(partial, gstart, gend, hg);
    k_mlp<<<NG, 64, 0, stream>>>(hg, Wm0, bm0, Wm1, bm1, Wm2, bm2, Wm3, bm3, out);
}